// Round 2
// baseline (1060.840 us; speedup 1.0000x reference)
//
#include <hip/hip_runtime.h>
#include <math.h>

typedef short bf16x8 __attribute__((ext_vector_type(8)));
typedef float f32x4 __attribute__((ext_vector_type(4)));
typedef float f32x2 __attribute__((ext_vector_type(2)));

__device__ __forceinline__ float bf2f(unsigned short u) {
    return __uint_as_float(((unsigned)u) << 16);
}
__device__ __forceinline__ unsigned short f2bf(float f) {
    unsigned u = __float_as_uint(f);
    unsigned r = u + 0x7FFF + ((u >> 16) & 1);   // RNE
    return (unsigned short)(r >> 16);
}
__device__ __forceinline__ unsigned char f2fp8(float f) {
    const int p = __builtin_amdgcn_cvt_pk_fp8_f32(f, f, 0, false);
    return (unsigned char)(p & 0xff);
}
__device__ __forceinline__ unsigned cvt_pk_bf16(float a, float b) {
    unsigned r;
    asm("v_cvt_pk_bf16_f32 %0, %1, %2" : "=v"(r) : "v"(a), "v"(b));
    return r;
}

#define GLD_LDS16(gp, lp)                                                     \
    __builtin_amdgcn_global_load_lds(                                         \
        (const __attribute__((address_space(1))) void*)(gp),                  \
        (__attribute__((address_space(3))) void*)(lp), 16, 0, 0)

// C[M,Ncols] = A[M,K] @ BT[Ncols,K]^T, fp32 acc via MFMA.
// AF32: A is fp32 (converted to bf16 at fragment read); else A is bf16.
// ASLICE: A is slice-major bf16 [K/32][M][32].
// OUTMODE: 0 = fp32 row-major, 1 = bf16 row-major, 2 = fp8 row-major,
//          3 = fp8 slice-major [Ncols/32][M][32].
// LDS chunk-XOR swizzle (write-side source permute + read-side XOR) kills the
// 8-way bank conflicts of power-of-2 row strides (2-way residual = free).
template <int BM, int BN, int OUTMODE, bool AF32, bool ASLICE>
__global__ __launch_bounds__(256) void gemm_mfma(const void* __restrict__ Av,
                                                 const unsigned short* __restrict__ BT,
                                                 void* __restrict__ Cv,
                                                 int M, int Ncols, int K) {
    constexpr int WM = BM / 2, WN = BN / 2, TM = WM / 16, TN = WN / 16;
    constexpr int ABYTES = BM * 32 * (AF32 ? 4 : 2);
    __shared__ __align__(16) char smem[ABYTES + BN * 32 * 2];
    float* Alf = (float*)smem;
    unsigned short* Al = (unsigned short*)smem;
    unsigned short* Bl = (unsigned short*)(smem + ABYTES);
    const float* Af = (const float*)Av;
    const unsigned short* Ab = (const unsigned short*)Av;

    const int tid = threadIdx.x;
    const int w = tid >> 6, lane = tid & 63;
    const int wm = w >> 1, wn = w & 1;
    const int row0 = blockIdx.x * BM, col0 = blockIdx.y * BN;
    const int q = lane >> 4, r = lane & 15;

    f32x4 acc[TM][TN];
    #pragma unroll
    for (int mt = 0; mt < TM; ++mt)
        #pragma unroll
        for (int nt = 0; nt < TN; ++nt) {
            f32x4 z = {0.f, 0.f, 0.f, 0.f};
            acc[mt][nt] = z;
        }

    for (int k0 = 0; k0 < K; k0 += 32) {
        __syncthreads();
        if (AF32) {
            // A tile: BM rows x 32 k fp32 (128 B/row = 8 x 16B chunks), XOR-swz
            #pragma unroll
            for (int i = 0; i < BM / 32; ++i) {
                const int idx = i * 256 + tid;
                const int arow = idx >> 3, pc = idx & 7;
                const int ch = pc ^ (arow & 7);
                int grow = row0 + arow;
                if (grow >= M) grow = M - 1;
                GLD_LDS16(Af + (size_t)grow * K + k0 + ch * 4,
                          Alf + (size_t)(i * 256 + w * 64) * 4);
            }
        } else {
            // A tile: BM rows x 32 k bf16 (64 B/row = 4 x 16B chunks), XOR-swz
            #pragma unroll
            for (int i = 0; i < BM / 64; ++i) {
                const int idx = i * 256 + tid;
                const int arow = idx >> 2, pc = idx & 3;
                const int ch = pc ^ ((arow >> 1) & 3);
                int grow = row0 + arow;
                if (grow >= M) grow = M - 1;
                const unsigned short* src =
                    ASLICE ? Ab + ((size_t)(k0 >> 5) * M + grow) * 32 + ch * 8
                           : Ab + (size_t)grow * K + k0 + ch * 8;
                GLD_LDS16(src, Al + (size_t)(i * 256 + w * 64) * 8);
            }
        }
        // BT tile: BN rows x 32 k bf16, XOR-swz
        #pragma unroll
        for (int i = 0; i < BN / 64; ++i) {
            const int idx = i * 256 + tid;
            const int brow = idx >> 2, pc = idx & 3;
            const int ch = pc ^ ((brow >> 1) & 3);
            GLD_LDS16(BT + (size_t)(col0 + brow) * K + k0 + ch * 8,
                      Bl + (size_t)(i * 256 + w * 64) * 8);
        }
        asm volatile("s_waitcnt vmcnt(0)" ::: "memory");
        __syncthreads();

        bf16x8 af[TM], bfr[TN];
        #pragma unroll
        for (int mt = 0; mt < TM; ++mt) {
            const int rr = wm * WM + mt * 16 + r;
            if (AF32) {
                const int s8 = rr & 7;
                const f32x4 lo = *(const f32x4*)&Alf[rr * 32 + ((2 * q) ^ s8) * 4];
                const f32x4 hi = *(const f32x4*)&Alf[rr * 32 + ((2 * q + 1) ^ s8) * 4];
                union { bf16x8 v; unsigned u[4]; } cv;
                cv.u[0] = cvt_pk_bf16(lo.x, lo.y);
                cv.u[1] = cvt_pk_bf16(lo.z, lo.w);
                cv.u[2] = cvt_pk_bf16(hi.x, hi.y);
                cv.u[3] = cvt_pk_bf16(hi.z, hi.w);
                af[mt] = cv.v;
            } else {
                af[mt] = *(const bf16x8*)&Al[rr * 32 + (q ^ ((rr >> 1) & 3)) * 8];
            }
        }
        #pragma unroll
        for (int nt = 0; nt < TN; ++nt) {
            const int rr = wn * WN + nt * 16 + r;
            bfr[nt] = *(const bf16x8*)&Bl[rr * 32 + (q ^ ((rr >> 1) & 3)) * 8];
        }
        #pragma unroll
        for (int mt = 0; mt < TM; ++mt)
            #pragma unroll
            for (int nt = 0; nt < TN; ++nt)
                acc[mt][nt] = __builtin_amdgcn_mfma_f32_16x16x32_bf16(
                    af[mt], bfr[nt], acc[mt][nt], 0, 0, 0);
    }

    #pragma unroll
    for (int mt = 0; mt < TM; ++mt) {
        #pragma unroll
        for (int nt = 0; nt < TN; ++nt) {
            const int gcol = col0 + wn * WN + nt * 16 + r;
            #pragma unroll
            for (int j = 0; j < 4; ++j) {
                const int grow = row0 + wm * WM + mt * 16 + q * 4 + j;
                if (grow < M) {
                    if (OUTMODE == 3) {
                        const int sl = gcol >> 5, f = gcol & 31;
                        ((unsigned char*)Cv)[((size_t)sl * M + grow) * 32 + f] =
                            f2fp8(acc[mt][nt][j]);
                    } else if (OUTMODE == 2) {
                        ((unsigned char*)Cv)[(size_t)grow * Ncols + gcol] = f2fp8(acc[mt][nt][j]);
                    } else if (OUTMODE == 1) {
                        ((unsigned short*)Cv)[(size_t)grow * Ncols + gcol] = f2bf(acc[mt][nt][j]);
                    } else {
                        ((float*)Cv)[(size_t)grow * Ncols + gcol] = acc[mt][nt][j];
                    }
                }
            }
        }
    }
}

// in: K x N fp32 -> out: N x K bf16 (transpose + cast); small matrices only.
__global__ __launch_bounds__(256) void transpose_cast(const float* __restrict__ in,
                                                      unsigned short* __restrict__ out,
                                                      int K, int N) {
    const int idx = blockIdx.x * 256 + threadIdx.x;
    if (idx < K * N) {
        const int k = idx / N, n = idx % N;
        out[(size_t)n * K + k] = f2bf(in[idx]);
    }
}

// ---- CSR build via bucketed 2-pass counting sort ----
// bucket = row >> 8 (256 rows/bucket).  NBMAX covers N up to 131072.
#define NBMAX 512
#define SB_CH 4096   // edges per block in scatter_bucket (16/thread)

__global__ __launch_bounds__(256) void bucket_hist(const int* __restrict__ rows,
                                                   int* __restrict__ bcnt, int E) {
    __shared__ int h[NBMAX];
    for (int i = threadIdx.x; i < NBMAX; i += 256) h[i] = 0;
    __syncthreads();
    for (long i = (long)blockIdx.x * 256 + threadIdx.x; i < E; i += (long)gridDim.x * 256)
        atomicAdd(&h[rows[i] >> 8], 1);
    __syncthreads();
    for (int i = threadIdx.x; i < NBMAX; i += 256)
        if (h[i]) atomicAdd(&bcnt[i], h[i]);
}

__global__ __launch_bounds__(512) void bucket_scan(const int* __restrict__ bcnt,
                                                   int* __restrict__ bstart, int nb) {
    __shared__ int s[NBMAX];
    const int t = threadIdx.x;
    const int v = (t < nb) ? bcnt[t] : 0;
    s[t] = v;
    __syncthreads();
    for (int o = 1; o < NBMAX; o <<= 1) {
        const int y = (t >= o) ? s[t - o] : 0;
        __syncthreads();
        s[t] += y;
        __syncthreads();
    }
    if (t < nb) bstart[t] = s[t] - v;
    if (t == nb - 1) bstart[nb] = s[t];
}

__global__ __launch_bounds__(256) void scatter_bucket(const int* __restrict__ rows,
                                                      const int* __restrict__ cols,
                                                      const float* __restrict__ vals,
                                                      const int* __restrict__ bstart,
                                                      int* __restrict__ bcursor,
                                                      int2* __restrict__ tmp, int E) {
    __shared__ int lcnt[NBMAX];
    __shared__ int lbase[NBMAX];
    const int t = threadIdx.x;
    const long c0 = (long)blockIdx.x * SB_CH;
    for (int i = t; i < NBMAX; i += 256) lcnt[i] = 0;
    __syncthreads();
    int rank[16], b[16];
    #pragma unroll
    for (int i = 0; i < 16; ++i) {
        const long e = c0 + i * 256 + t;
        if (e < E) {
            b[i] = rows[e] >> 8;
            rank[i] = atomicAdd(&lcnt[b[i]], 1);
        }
    }
    __syncthreads();
    for (int i = t; i < NBMAX; i += 256)
        lbase[i] = lcnt[i] ? atomicAdd(&bcursor[i], lcnt[i]) : 0;
    __syncthreads();
    #pragma unroll
    for (int i = 0; i < 16; ++i) {
        const long e = c0 + i * 256 + t;
        if (e < E) {
            const int r = rows[e];
            const int pos = bstart[b[i]] + lbase[b[i]] + rank[i];
            tmp[pos] = make_int2(((r & 255) << 17) | cols[e], __float_as_int(vals[e]));
        }
    }
}

__global__ __launch_bounds__(256) void bucket_to_csr(const int2* __restrict__ tmp,
                                                     const int* __restrict__ bstart,
                                                     int* __restrict__ rs,
                                                     int2* __restrict__ edges,
                                                     int N, int nb, int E) {
    __shared__ int rcnt[256];
    __shared__ int rsc[256];
    const int b = blockIdx.x;
    const int t = threadIdx.x;
    const int s = bstart[b], e = bstart[b + 1];
    rcnt[t] = 0;
    __syncthreads();
    for (int i = s + t; i < e; i += 256)
        atomicAdd(&rcnt[tmp[i].x >> 17], 1);
    __syncthreads();
    const int v = rcnt[t];
    rsc[t] = v;
    __syncthreads();
    for (int o = 1; o < 256; o <<= 1) {
        const int y = (t >= o) ? rsc[t - o] : 0;
        __syncthreads();
        rsc[t] += y;
        __syncthreads();
    }
    const int excl = rsc[t] - v;
    const int grow = b * 256 + t;
    if (grow < N) rs[grow] = s + excl;
    if (b == nb - 1 && t == 0) rs[N] = E;
    __syncthreads();
    rcnt[t] = s + excl;
    __syncthreads();
    for (int i = s + t; i < e; i += 256) {
        const int2 x = tmp[i];
        const int pos = atomicAdd(&rcnt[x.x >> 17], 1);
        edges[pos] = make_int2(x.x & 0x1FFFF, x.y);
    }
}

// ---- feature-sliced CSR spmm, F=256 as 8 passes of 32 features ----
// X slice-major [8][N][32B fp8]: per pass the 3.2 MB slice is L2-resident.
// Lanes: e_sub = lane>>3 (8 edges/iter), fg = lane&7 (4 packed fp8 features).
// Y slice-major [8][N][32] bf16 (gemm2 stages it slice-wise).
__global__ __launch_bounds__(256) void spmm_slice_relu(const int2* __restrict__ edges,
                                                       const int* __restrict__ rs,
                                                       const unsigned char* __restrict__ X,
                                                       const float* __restrict__ bias,
                                                       unsigned short* __restrict__ Y, int N) {
    const int pass = blockIdx.y;
    const int row = blockIdx.x * 4 + (threadIdx.x >> 6);
    if (row >= N) return;
    const int lane = threadIdx.x & 63;
    const int es = lane >> 3;
    const int fg = lane & 7;
    const unsigned char* Xs = X + (size_t)pass * N * 32;
    const int s = rs[row], e = rs[row + 1];
    float a0 = 0.f, a1 = 0.f, a2 = 0.f, a3 = 0.f;
    const int efull = s + ((e - s) & ~7);
    int i = s;
    for (; i < efull; i += 8) {
        const int2 ed = edges[i + es];
        const float v = __int_as_float(ed.y);
        const unsigned xw = *(const unsigned*)(Xs + (size_t)ed.x * 32 + fg * 4);
        const f32x2 l = __builtin_amdgcn_cvt_pk_f32_fp8(xw, false);
        const f32x2 h = __builtin_amdgcn_cvt_pk_f32_fp8(xw, true);
        a0 += v * l.x; a1 += v * l.y; a2 += v * h.x; a3 += v * h.y;
    }
    if (i < e) {
        const int idx = i + es;
        const int2 ed = (idx < e) ? edges[idx] : make_int2(0, 0);
        const float v = __int_as_float(ed.y);
        const unsigned xw = *(const unsigned*)(Xs + (size_t)ed.x * 32 + fg * 4);
        const f32x2 l = __builtin_amdgcn_cvt_pk_f32_fp8(xw, false);
        const f32x2 h = __builtin_amdgcn_cvt_pk_f32_fp8(xw, true);
        a0 += v * l.x; a1 += v * l.y; a2 += v * h.x; a3 += v * h.y;
    }
    #pragma unroll
    for (int m = 8; m <= 32; m <<= 1) {
        a0 += __shfl_xor(a0, m);
        a1 += __shfl_xor(a1, m);
        a2 += __shfl_xor(a2, m);
        a3 += __shfl_xor(a3, m);
    }
    if (es == 0) {
        const float4 bb = ((const float4*)bias)[pass * 8 + fg];
        ushort4 o;
        o.x = f2bf(fmaxf(a0 + bb.x, 0.f));
        o.y = f2bf(fmaxf(a1 + bb.y, 0.f));
        o.z = f2bf(fmaxf(a2 + bb.z, 0.f));
        o.w = f2bf(fmaxf(a3 + bb.w, 0.f));
        ((ushort4*)(Y + ((size_t)pass * N + row) * 32))[fg] = o;
    }
}

// F=64 (fp8 X row-major), fused bias + log_softmax, fp32 out. Unroll x4.
__global__ __launch_bounds__(256) void spmm_csr64_lsm(const int2* __restrict__ edges,
                                                      const int* __restrict__ rs,
                                                      const unsigned char* __restrict__ X,
                                                      const float* __restrict__ bias,
                                                      float* __restrict__ out, int N) {
    const int row = blockIdx.x * 4 + (threadIdx.x >> 6);
    if (row >= N) return;
    const int lane = threadIdx.x & 63;
    const int s = rs[row], e = rs[row + 1];
    float acc = 0.f;
    int i = s;
    for (; i + 3 < e; i += 4) {
        const int2 e0 = edges[i];
        const int2 e1 = edges[i + 1];
        const int2 e2 = edges[i + 2];
        const int2 e3 = edges[i + 3];
        const int u0 = X[(size_t)e0.x * 64 + lane];
        const int u1 = X[(size_t)e1.x * 64 + lane];
        const int u2 = X[(size_t)e2.x * 64 + lane];
        const int u3 = X[(size_t)e3.x * 64 + lane];
        const float x0 = __builtin_amdgcn_cvt_f32_fp8(u0, 0);
        const float x1 = __builtin_amdgcn_cvt_f32_fp8(u1, 0);
        const float x2 = __builtin_amdgcn_cvt_f32_fp8(u2, 0);
        const float x3 = __builtin_amdgcn_cvt_f32_fp8(u3, 0);
        acc += __int_as_float(e0.y) * x0 + __int_as_float(e1.y) * x1
             + __int_as_float(e2.y) * x2 + __int_as_float(e3.y) * x3;
    }
    for (; i < e; ++i) {
        const int2 e0 = edges[i];
        const int u0 = X[(size_t)e0.x * 64 + lane];
        acc += __int_as_float(e0.y) * __builtin_amdgcn_cvt_f32_fp8(u0, 0);
    }
    float v = acc + bias[lane];
    float m = v;
    #pragma unroll
    for (int o = 32; o; o >>= 1) m = fmaxf(m, __shfl_xor(m, o));
    const float ex = __expf(v - m);
    float ssum = ex;
    #pragma unroll
    for (int o = 32; o; o >>= 1) ssum += __shfl_xor(ssum, o);
    out[(size_t)row * 64 + lane] = v - m - __logf(ssum);
}

extern "C" void kernel_launch(void* const* d_in, const int* in_sizes, int n_in,
                              void* d_out, int out_size, void* d_ws, size_t ws_size,
                              hipStream_t stream) {
    const float* x    = (const float*)d_in[0];
    const int*   erow = (const int*)d_in[1];
    const int*   ecol = (const int*)d_in[2];
    const float* eval = (const float*)d_in[3];
    const float* W1   = (const float*)d_in[4];
    const float* b1   = (const float*)d_in[5];
    const float* W2   = (const float*)d_in[6];
    const float* b2   = (const float*)d_in[7];
    float* out = (float*)d_out;

    const int E      = in_sizes[1];
    const int nhid   = in_sizes[5];              // 256
    const int nclass = in_sizes[7];              // 64
    const int nfeat  = in_sizes[4] / nhid;       // 512
    const int N      = in_sizes[0] / nfeat;      // 100000

    // workspace layout (~104 MB, aliased regions noted)
    char* w = (char*)d_ws;
    unsigned short* h1b = (unsigned short*)w;     // [8][N][32] bf16 slice-major (51.2 MB)
    int2* tmp = (int2*)w;                         // aliases h1b during CSR build (E*8)
    w += (size_t)N * nhid * 2;
    unsigned char* h0q = (unsigned char*)w;       // [8][N][32] fp8 slice-major (25.6 MB)
    unsigned char* h2q = h0q;                     // aliases h0q after spmm1 ([N][64] fp8)
    w += (size_t)N * nhid;
    int2* edges = (int2*)w;                       w += (size_t)E * 8;
    int* rs = (int*)w;                            w += (size_t)(N + 1) * 4;
    int* bcnt = (int*)w;                          w += NBMAX * 4;
    int* bcursor = (int*)w;                       w += NBMAX * 4;
    int* bstart = (int*)w;                        w += (NBMAX + 1) * 4;
    unsigned short* W1T = (unsigned short*)w;     w += (size_t)nfeat * nhid * 2;
    unsigned short* W2T = (unsigned short*)w;     w += (size_t)nhid * nclass * 2;

    const int nb = (N + 255) >> 8;                // 391 buckets of 256 rows

    // CSR build: bucketed 2-pass counting sort (shared by both spmm layers)
    hipMemsetAsync(bcnt, 0, (size_t)2 * NBMAX * sizeof(int), stream);  // bcnt + bcursor
    bucket_hist<<<512, 256, 0, stream>>>(erow, bcnt, E);
    bucket_scan<<<1, NBMAX, 0, stream>>>(bcnt, bstart, nb);
    scatter_bucket<<<(E + SB_CH - 1) / SB_CH, 256, 0, stream>>>(erow, ecol, eval, bstart,
                                                                bcursor, tmp, E);
    bucket_to_csr<<<nb, 256, 0, stream>>>(tmp, bstart, rs, edges, N, nb, E);

    // weight transposes (tiny)
    transpose_cast<<<(nfeat * nhid + 255) / 256, 256, 0, stream>>>(W1, W1T, nfeat, nhid);
    transpose_cast<<<(nhid * nclass + 255) / 256, 256, 0, stream>>>(W2, W2T, nhid, nclass);

    // layer 1: h0q = fp8_slicemajor(x @ W1) — fp32 A staged directly (no cast pass)
    dim3 g1((N + 127) / 128, nhid / 256);
    gemm_mfma<128, 256, 3, true, false><<<g1, 256, 0, stream>>>(x, W1T, h0q, N, nhid, nfeat);
    // h1b = bf16_slicemajor(relu(spmm(h0q) + b1)) — 8 phased passes, L2-resident slices
    dim3 gs((N + 3) / 4, 8);
    spmm_slice_relu<<<gs, 256, 0, stream>>>(edges, rs, h0q, b1, h1b, N);

    // layer 2: h2q = fp8(h1b @ W2), A slice-major
    dim3 g2((N + 127) / 128, nclass / 64);
    gemm_mfma<128, 64, 2, false, true><<<g2, 256, 0, stream>>>(h1b, W2T, h2q, N, nclass, nhid);
    // out = log_softmax(spmm(h2q) + b2)
    spmm_csr64_lsm<<<(N + 3) / 4, 256, 0, stream>>>(edges, rs, h2q, b2, out, N);
}

// Round 3
// 730.866 us; speedup vs baseline: 1.4515x; 1.4515x over previous
//
#include <hip/hip_runtime.h>
#include <math.h>

typedef short bf16x8 __attribute__((ext_vector_type(8)));
typedef float f32x4 __attribute__((ext_vector_type(4)));
typedef float f32x2 __attribute__((ext_vector_type(2)));

__device__ __forceinline__ float bf2f(unsigned short u) {
    return __uint_as_float(((unsigned)u) << 16);
}
__device__ __forceinline__ unsigned short f2bf(float f) {
    unsigned u = __float_as_uint(f);
    unsigned r = u + 0x7FFF + ((u >> 16) & 1);   // RNE
    return (unsigned short)(r >> 16);
}
__device__ __forceinline__ unsigned char f2fp8(float f) {
    const int p = __builtin_amdgcn_cvt_pk_fp8_f32(f, f, 0, false);
    return (unsigned char)(p & 0xff);
}
__device__ __forceinline__ unsigned cvt_pk_bf16(float a, float b) {
    unsigned r;
    asm("v_cvt_pk_bf16_f32 %0, %1, %2" : "=v"(r) : "v"(a), "v"(b));
    return r;
}

#define GLD_LDS16(gp, lp)                                                     \
    __builtin_amdgcn_global_load_lds(                                         \
        (const __attribute__((address_space(1))) void*)(gp),                  \
        (__attribute__((address_space(3))) void*)(lp), 16, 0, 0)

// C[M,Ncols] = A[M,K] @ BT[Ncols,K]^T, fp32 acc via MFMA.
// AF32: A is fp32 (converted to bf16 at fragment read); else A is bf16.
// OUTMODE: 0 = fp32, 1 = bf16, 2 = fp8 e4m3 (all row-major).
// LDS chunk-XOR swizzle (write-side source permute + read-side XOR) kills the
// 8-way bank conflicts of power-of-2 row strides (2-way residual = free).
template <int BM, int BN, int OUTMODE, bool AF32>
__global__ __launch_bounds__(256) void gemm_mfma(const void* __restrict__ Av,
                                                 const unsigned short* __restrict__ BT,
                                                 void* __restrict__ Cv,
                                                 int M, int Ncols, int K) {
    constexpr int WM = BM / 2, WN = BN / 2, TM = WM / 16, TN = WN / 16;
    constexpr int ABYTES = BM * 32 * (AF32 ? 4 : 2);
    __shared__ __align__(16) char smem[ABYTES + BN * 32 * 2];
    float* Alf = (float*)smem;
    unsigned short* Al = (unsigned short*)smem;
    unsigned short* Bl = (unsigned short*)(smem + ABYTES);
    const float* Af = (const float*)Av;
    const unsigned short* Ab = (const unsigned short*)Av;

    const int tid = threadIdx.x;
    const int w = tid >> 6, lane = tid & 63;
    const int wm = w >> 1, wn = w & 1;
    const int row0 = blockIdx.x * BM, col0 = blockIdx.y * BN;
    const int q = lane >> 4, r = lane & 15;

    f32x4 acc[TM][TN];
    #pragma unroll
    for (int mt = 0; mt < TM; ++mt)
        #pragma unroll
        for (int nt = 0; nt < TN; ++nt) {
            f32x4 z = {0.f, 0.f, 0.f, 0.f};
            acc[mt][nt] = z;
        }

    for (int k0 = 0; k0 < K; k0 += 32) {
        __syncthreads();
        if (AF32) {
            // A tile: BM rows x 32 k fp32 (128 B/row = 8 x 16B chunks), XOR-swz
            #pragma unroll
            for (int i = 0; i < BM / 32; ++i) {
                const int idx = i * 256 + tid;
                const int arow = idx >> 3, pc = idx & 7;
                const int ch = pc ^ (arow & 7);
                int grow = row0 + arow;
                if (grow >= M) grow = M - 1;
                GLD_LDS16(Af + (size_t)grow * K + k0 + ch * 4,
                          Alf + (size_t)(i * 256 + w * 64) * 4);
            }
        } else {
            // A tile: BM rows x 32 k bf16 (64 B/row = 4 x 16B chunks), XOR-swz
            #pragma unroll
            for (int i = 0; i < BM / 64; ++i) {
                const int idx = i * 256 + tid;
                const int arow = idx >> 2, pc = idx & 3;
                const int ch = pc ^ ((arow >> 1) & 3);
                int grow = row0 + arow;
                if (grow >= M) grow = M - 1;
                GLD_LDS16(Ab + (size_t)grow * K + k0 + ch * 8,
                          Al + (size_t)(i * 256 + w * 64) * 8);
            }
        }
        // BT tile: BN rows x 32 k bf16, XOR-swz
        #pragma unroll
        for (int i = 0; i < BN / 64; ++i) {
            const int idx = i * 256 + tid;
            const int brow = idx >> 2, pc = idx & 3;
            const int ch = pc ^ ((brow >> 1) & 3);
            GLD_LDS16(BT + (size_t)(col0 + brow) * K + k0 + ch * 8,
                      Bl + (size_t)(i * 256 + w * 64) * 8);
        }
        asm volatile("s_waitcnt vmcnt(0)" ::: "memory");
        __syncthreads();

        bf16x8 af[TM], bfr[TN];
        #pragma unroll
        for (int mt = 0; mt < TM; ++mt) {
            const int rr = wm * WM + mt * 16 + r;
            if (AF32) {
                const int s8 = rr & 7;
                const f32x4 lo = *(const f32x4*)&Alf[rr * 32 + ((2 * q) ^ s8) * 4];
                const f32x4 hi = *(const f32x4*)&Alf[rr * 32 + ((2 * q + 1) ^ s8) * 4];
                union { bf16x8 v; unsigned u[4]; } cv;
                cv.u[0] = cvt_pk_bf16(lo.x, lo.y);
                cv.u[1] = cvt_pk_bf16(lo.z, lo.w);
                cv.u[2] = cvt_pk_bf16(hi.x, hi.y);
                cv.u[3] = cvt_pk_bf16(hi.z, hi.w);
                af[mt] = cv.v;
            } else {
                af[mt] = *(const bf16x8*)&Al[rr * 32 + (q ^ ((rr >> 1) & 3)) * 8];
            }
        }
        #pragma unroll
        for (int nt = 0; nt < TN; ++nt) {
            const int rr = wn * WN + nt * 16 + r;
            bfr[nt] = *(const bf16x8*)&Bl[rr * 32 + (q ^ ((rr >> 1) & 3)) * 8];
        }
        #pragma unroll
        for (int mt = 0; mt < TM; ++mt)
            #pragma unroll
            for (int nt = 0; nt < TN; ++nt)
                acc[mt][nt] = __builtin_amdgcn_mfma_f32_16x16x32_bf16(
                    af[mt], bfr[nt], acc[mt][nt], 0, 0, 0);
    }

    #pragma unroll
    for (int mt = 0; mt < TM; ++mt) {
        #pragma unroll
        for (int nt = 0; nt < TN; ++nt) {
            const int gcol = col0 + wn * WN + nt * 16 + r;
            #pragma unroll
            for (int j = 0; j < 4; ++j) {
                const int grow = row0 + wm * WM + mt * 16 + q * 4 + j;
                if (grow < M) {
                    if (OUTMODE == 2)
                        ((unsigned char*)Cv)[(size_t)grow * Ncols + gcol] = f2fp8(acc[mt][nt][j]);
                    else if (OUTMODE == 1)
                        ((unsigned short*)Cv)[(size_t)grow * Ncols + gcol] = f2bf(acc[mt][nt][j]);
                    else
                        ((float*)Cv)[(size_t)grow * Ncols + gcol] = acc[mt][nt][j];
                }
            }
        }
    }
}

// in: K x N fp32 -> out: N x K bf16 (transpose + cast); small matrices only.
__global__ __launch_bounds__(256) void transpose_cast(const float* __restrict__ in,
                                                      unsigned short* __restrict__ out,
                                                      int K, int N) {
    const int idx = blockIdx.x * 256 + threadIdx.x;
    if (idx < K * N) {
        const int k = idx / N, n = idx % N;
        out[(size_t)n * K + k] = f2bf(in[idx]);
    }
}

// ---- CSR build via bucketed 2-pass counting sort ----
// bucket = row >> 8 (256 rows/bucket).  NBMAX covers N up to 131072.
#define NBMAX 512
#define SB_CH 4096   // edges per block in scatter_bucket (16/thread)

__global__ __launch_bounds__(256) void bucket_hist(const int* __restrict__ rows,
                                                   int* __restrict__ bcnt, int E) {
    __shared__ int h[NBMAX];
    for (int i = threadIdx.x; i < NBMAX; i += 256) h[i] = 0;
    __syncthreads();
    for (long i = (long)blockIdx.x * 256 + threadIdx.x; i < E; i += (long)gridDim.x * 256)
        atomicAdd(&h[rows[i] >> 8], 1);
    __syncthreads();
    for (int i = threadIdx.x; i < NBMAX; i += 256)
        if (h[i]) atomicAdd(&bcnt[i], h[i]);
}

__global__ __launch_bounds__(512) void bucket_scan(const int* __restrict__ bcnt,
                                                   int* __restrict__ bstart, int nb) {
    __shared__ int s[NBMAX];
    const int t = threadIdx.x;
    const int v = (t < nb) ? bcnt[t] : 0;
    s[t] = v;
    __syncthreads();
    for (int o = 1; o < NBMAX; o <<= 1) {
        const int y = (t >= o) ? s[t - o] : 0;
        __syncthreads();
        s[t] += y;
        __syncthreads();
    }
    if (t < nb) bstart[t] = s[t] - v;
    if (t == nb - 1) bstart[nb] = s[t];
}

__global__ __launch_bounds__(256) void scatter_bucket(const int* __restrict__ rows,
                                                      const int* __restrict__ cols,
                                                      const float* __restrict__ vals,
                                                      const int* __restrict__ bstart,
                                                      int* __restrict__ bcursor,
                                                      int2* __restrict__ tmp, int E) {
    __shared__ int lcnt[NBMAX];
    __shared__ int lbase[NBMAX];
    const int t = threadIdx.x;
    const long c0 = (long)blockIdx.x * SB_CH;
    for (int i = t; i < NBMAX; i += 256) lcnt[i] = 0;
    __syncthreads();
    int rank[16], b[16];
    #pragma unroll
    for (int i = 0; i < 16; ++i) {
        const long e = c0 + i * 256 + t;
        if (e < E) {
            b[i] = rows[e] >> 8;
            rank[i] = atomicAdd(&lcnt[b[i]], 1);
        }
    }
    __syncthreads();
    for (int i = t; i < NBMAX; i += 256)
        lbase[i] = lcnt[i] ? atomicAdd(&bcursor[i], lcnt[i]) : 0;
    __syncthreads();
    #pragma unroll
    for (int i = 0; i < 16; ++i) {
        const long e = c0 + i * 256 + t;
        if (e < E) {
            const int r = rows[e];
            const int pos = bstart[b[i]] + lbase[b[i]] + rank[i];
            tmp[pos] = make_int2(((r & 255) << 17) | cols[e], __float_as_int(vals[e]));
        }
    }
}

__global__ __launch_bounds__(256) void bucket_to_csr(const int2* __restrict__ tmp,
                                                     const int* __restrict__ bstart,
                                                     int* __restrict__ rs,
                                                     int2* __restrict__ edges,
                                                     int N, int nb, int E) {
    __shared__ int rcnt[256];
    __shared__ int rsc[256];
    const int b = blockIdx.x;
    const int t = threadIdx.x;
    const int s = bstart[b], e = bstart[b + 1];
    rcnt[t] = 0;
    __syncthreads();
    for (int i = s + t; i < e; i += 256)
        atomicAdd(&rcnt[tmp[i].x >> 17], 1);
    __syncthreads();
    const int v = rcnt[t];
    rsc[t] = v;
    __syncthreads();
    for (int o = 1; o < 256; o <<= 1) {
        const int y = (t >= o) ? rsc[t - o] : 0;
        __syncthreads();
        rsc[t] += y;
        __syncthreads();
    }
    const int excl = rsc[t] - v;
    const int grow = b * 256 + t;
    if (grow < N) rs[grow] = s + excl;
    if (b == nb - 1 && t == 0) rs[N] = E;
    __syncthreads();
    rcnt[t] = s + excl;
    __syncthreads();
    for (int i = s + t; i < e; i += 256) {
        const int2 x = tmp[i];
        const int pos = atomicAdd(&rcnt[x.x >> 17], 1);
        edges[pos] = make_int2(x.x & 0x1FFFF, x.y);
    }
}

// ---- CSR spmm ----
// F=256 (fp8 X row-major), fused bias+relu, bf16 out.
// 8-edge unroll: edge records read as wave-uniform int4 pairs (scalar-load
// eligible via readfirstlane'd row), 8 independent 4B/lane gathers in flight.
__global__ __launch_bounds__(256) void spmm_csr256_relu(const int2* __restrict__ edges,
                                                        const int* __restrict__ rs,
                                                        const unsigned char* __restrict__ X,
                                                        const float* __restrict__ bias,
                                                        unsigned short* __restrict__ Y, int N) {
    const int row = __builtin_amdgcn_readfirstlane(blockIdx.x * 4 + (threadIdx.x >> 6));
    if (row >= N) return;
    const int lane = threadIdx.x & 63;
    const int s = rs[row], e = rs[row + 1];
    float a0 = 0.f, a1 = 0.f, a2 = 0.f, a3 = 0.f;
    int i = s;

#define SP256_ONE(col, vbits)                                                 \
    {                                                                         \
        const unsigned xw = ((const unsigned*)(X + (size_t)(col) * 256))[lane]; \
        const float v = __int_as_float(vbits);                                \
        const f32x2 l = __builtin_amdgcn_cvt_pk_f32_fp8(xw, false);           \
        const f32x2 h = __builtin_amdgcn_cvt_pk_f32_fp8(xw, true);            \
        a0 += v * l.x; a1 += v * l.y; a2 += v * h.x; a3 += v * h.y;           \
    }

    if ((i & 1) && i < e) {   // peel to 16B-align the int4 edge loads
        const int2 e0 = edges[i];
        SP256_ONE(e0.x, e0.y);
        ++i;
    }
    for (; i + 8 <= e; i += 8) {
        const int4 q0 = *(const int4*)(edges + i);
        const int4 q1 = *(const int4*)(edges + i + 2);
        const int4 q2 = *(const int4*)(edges + i + 4);
        const int4 q3 = *(const int4*)(edges + i + 6);
        const unsigned x0 = ((const unsigned*)(X + (size_t)q0.x * 256))[lane];
        const unsigned x1 = ((const unsigned*)(X + (size_t)q0.z * 256))[lane];
        const unsigned x2 = ((const unsigned*)(X + (size_t)q1.x * 256))[lane];
        const unsigned x3 = ((const unsigned*)(X + (size_t)q1.z * 256))[lane];
        const unsigned x4 = ((const unsigned*)(X + (size_t)q2.x * 256))[lane];
        const unsigned x5 = ((const unsigned*)(X + (size_t)q2.z * 256))[lane];
        const unsigned x6 = ((const unsigned*)(X + (size_t)q3.x * 256))[lane];
        const unsigned x7 = ((const unsigned*)(X + (size_t)q3.z * 256))[lane];
        const float v0 = __int_as_float(q0.y), v1 = __int_as_float(q0.w);
        const float v2 = __int_as_float(q1.y), v3 = __int_as_float(q1.w);
        const float v4 = __int_as_float(q2.y), v5 = __int_as_float(q2.w);
        const float v6 = __int_as_float(q3.y), v7 = __int_as_float(q3.w);
        const f32x2 l0 = __builtin_amdgcn_cvt_pk_f32_fp8(x0, false);
        const f32x2 h0 = __builtin_amdgcn_cvt_pk_f32_fp8(x0, true);
        const f32x2 l1 = __builtin_amdgcn_cvt_pk_f32_fp8(x1, false);
        const f32x2 h1 = __builtin_amdgcn_cvt_pk_f32_fp8(x1, true);
        const f32x2 l2 = __builtin_amdgcn_cvt_pk_f32_fp8(x2, false);
        const f32x2 h2 = __builtin_amdgcn_cvt_pk_f32_fp8(x2, true);
        const f32x2 l3 = __builtin_amdgcn_cvt_pk_f32_fp8(x3, false);
        const f32x2 h3 = __builtin_amdgcn_cvt_pk_f32_fp8(x3, true);
        const f32x2 l4 = __builtin_amdgcn_cvt_pk_f32_fp8(x4, false);
        const f32x2 h4 = __builtin_amdgcn_cvt_pk_f32_fp8(x4, true);
        const f32x2 l5 = __builtin_amdgcn_cvt_pk_f32_fp8(x5, false);
        const f32x2 h5 = __builtin_amdgcn_cvt_pk_f32_fp8(x5, true);
        const f32x2 l6 = __builtin_amdgcn_cvt_pk_f32_fp8(x6, false);
        const f32x2 h6 = __builtin_amdgcn_cvt_pk_f32_fp8(x6, true);
        const f32x2 l7 = __builtin_amdgcn_cvt_pk_f32_fp8(x7, false);
        const f32x2 h7 = __builtin_amdgcn_cvt_pk_f32_fp8(x7, true);
        a0 += v0 * l0.x + v1 * l1.x + v2 * l2.x + v3 * l3.x
            + v4 * l4.x + v5 * l5.x + v6 * l6.x + v7 * l7.x;
        a1 += v0 * l0.y + v1 * l1.y + v2 * l2.y + v3 * l3.y
            + v4 * l4.y + v5 * l5.y + v6 * l6.y + v7 * l7.y;
        a2 += v0 * h0.x + v1 * h1.x + v2 * h2.x + v3 * h3.x
            + v4 * h4.x + v5 * h5.x + v6 * h6.x + v7 * h7.x;
        a3 += v0 * h0.y + v1 * h1.y + v2 * h2.y + v3 * h3.y
            + v4 * h4.y + v5 * h5.y + v6 * h6.y + v7 * h7.y;
    }
    for (; i < e; ++i) {
        const int2 e0 = edges[i];
        SP256_ONE(e0.x, e0.y);
    }
#undef SP256_ONE

    const float4 bb = ((const float4*)bias)[lane];
    ushort4 o;
    o.x = f2bf(fmaxf(a0 + bb.x, 0.f));
    o.y = f2bf(fmaxf(a1 + bb.y, 0.f));
    o.z = f2bf(fmaxf(a2 + bb.z, 0.f));
    o.w = f2bf(fmaxf(a3 + bb.w, 0.f));
    ((ushort4*)(Y + (size_t)row * 256))[lane] = o;
}

// F=64 (fp8 X row-major), fused bias + log_softmax, fp32 out. 8-edge unroll.
__global__ __launch_bounds__(256) void spmm_csr64_lsm(const int2* __restrict__ edges,
                                                      const int* __restrict__ rs,
                                                      const unsigned char* __restrict__ X,
                                                      const float* __restrict__ bias,
                                                      float* __restrict__ out, int N) {
    const int row = __builtin_amdgcn_readfirstlane(blockIdx.x * 4 + (threadIdx.x >> 6));
    if (row >= N) return;
    const int lane = threadIdx.x & 63;
    const int s = rs[row], e = rs[row + 1];
    float acc = 0.f;
    int i = s;

#define SP64_ONE(col, vbits)                                                  \
    {                                                                         \
        const int u = X[(size_t)(col) * 64 + lane];                           \
        acc += __int_as_float(vbits) * __builtin_amdgcn_cvt_f32_fp8(u, 0);    \
    }

    if ((i & 1) && i < e) {
        const int2 e0 = edges[i];
        SP64_ONE(e0.x, e0.y);
        ++i;
    }
    for (; i + 8 <= e; i += 8) {
        const int4 q0 = *(const int4*)(edges + i);
        const int4 q1 = *(const int4*)(edges + i + 2);
        const int4 q2 = *(const int4*)(edges + i + 4);
        const int4 q3 = *(const int4*)(edges + i + 6);
        const int u0 = X[(size_t)q0.x * 64 + lane];
        const int u1 = X[(size_t)q0.z * 64 + lane];
        const int u2 = X[(size_t)q1.x * 64 + lane];
        const int u3 = X[(size_t)q1.z * 64 + lane];
        const int u4 = X[(size_t)q2.x * 64 + lane];
        const int u5 = X[(size_t)q2.z * 64 + lane];
        const int u6 = X[(size_t)q3.x * 64 + lane];
        const int u7 = X[(size_t)q3.z * 64 + lane];
        acc += __int_as_float(q0.y) * __builtin_amdgcn_cvt_f32_fp8(u0, 0)
             + __int_as_float(q0.w) * __builtin_amdgcn_cvt_f32_fp8(u1, 0)
             + __int_as_float(q1.y) * __builtin_amdgcn_cvt_f32_fp8(u2, 0)
             + __int_as_float(q1.w) * __builtin_amdgcn_cvt_f32_fp8(u3, 0)
             + __int_as_float(q2.y) * __builtin_amdgcn_cvt_f32_fp8(u4, 0)
             + __int_as_float(q2.w) * __builtin_amdgcn_cvt_f32_fp8(u5, 0)
             + __int_as_float(q3.y) * __builtin_amdgcn_cvt_f32_fp8(u6, 0)
             + __int_as_float(q3.w) * __builtin_amdgcn_cvt_f32_fp8(u7, 0);
    }
    for (; i < e; ++i) {
        const int2 e0 = edges[i];
        SP64_ONE(e0.x, e0.y);
    }
#undef SP64_ONE

    float v = acc + bias[lane];
    float m = v;
    #pragma unroll
    for (int o = 32; o; o >>= 1) m = fmaxf(m, __shfl_xor(m, o));
    const float ex = __expf(v - m);
    float ssum = ex;
    #pragma unroll
    for (int o = 32; o; o >>= 1) ssum += __shfl_xor(ssum, o);
    out[(size_t)row * 64 + lane] = v - m - __logf(ssum);
}

extern "C" void kernel_launch(void* const* d_in, const int* in_sizes, int n_in,
                              void* d_out, int out_size, void* d_ws, size_t ws_size,
                              hipStream_t stream) {
    const float* x    = (const float*)d_in[0];
    const int*   erow = (const int*)d_in[1];
    const int*   ecol = (const int*)d_in[2];
    const float* eval = (const float*)d_in[3];
    const float* W1   = (const float*)d_in[4];
    const float* b1   = (const float*)d_in[5];
    const float* W2   = (const float*)d_in[6];
    const float* b2   = (const float*)d_in[7];
    float* out = (float*)d_out;

    const int E      = in_sizes[1];
    const int nhid   = in_sizes[5];              // 256
    const int nclass = in_sizes[7];              // 64
    const int nfeat  = in_sizes[4] / nhid;       // 512
    const int N      = in_sizes[0] / nfeat;      // 100000

    // workspace layout (~104 MB, aliased regions noted)
    char* w = (char*)d_ws;
    unsigned short* h1b = (unsigned short*)w;     // [N][256] bf16 row-major (51.2 MB)
    int2* tmp = (int2*)w;                         // aliases h1b during CSR build (E*8)
    w += (size_t)N * nhid * 2;
    unsigned char* h0q = (unsigned char*)w;       // [N][256] fp8 row-major (25.6 MB)
    unsigned char* h2q = h0q;                     // aliases h0q after spmm1 ([N][64] fp8)
    w += (size_t)N * nhid;
    int2* edges = (int2*)w;                       w += (size_t)E * 8;
    int* rs = (int*)w;                            w += (size_t)(N + 1) * 4;
    int* bcnt = (int*)w;                          w += NBMAX * 4;
    int* bcursor = (int*)w;                       w += NBMAX * 4;
    int* bstart = (int*)w;                        w += (NBMAX + 1) * 4;
    unsigned short* W1T = (unsigned short*)w;     w += (size_t)nfeat * nhid * 2;
    unsigned short* W2T = (unsigned short*)w;     w += (size_t)nhid * nclass * 2;

    const int nb = (N + 255) >> 8;                // 391 buckets of 256 rows

    // CSR build: bucketed 2-pass counting sort (shared by both spmm layers)
    hipMemsetAsync(bcnt, 0, (size_t)2 * NBMAX * sizeof(int), stream);  // bcnt + bcursor
    bucket_hist<<<512, 256, 0, stream>>>(erow, bcnt, E);
    bucket_scan<<<1, NBMAX, 0, stream>>>(bcnt, bstart, nb);
    scatter_bucket<<<(E + SB_CH - 1) / SB_CH, 256, 0, stream>>>(erow, ecol, eval, bstart,
                                                                bcursor, tmp, E);
    bucket_to_csr<<<nb, 256, 0, stream>>>(tmp, bstart, rs, edges, N, nb, E);

    // weight transposes (tiny)
    transpose_cast<<<(nfeat * nhid + 255) / 256, 256, 0, stream>>>(W1, W1T, nfeat, nhid);
    transpose_cast<<<(nhid * nclass + 255) / 256, 256, 0, stream>>>(W2, W2T, nhid, nclass);

    // layer 1: h0q = fp8(x @ W1) — fp32 A staged directly into LDS (no cast pass)
    dim3 g1((N + 127) / 128, nhid / 256);
    gemm_mfma<128, 256, 2, true><<<g1, 256, 0, stream>>>(x, W1T, h0q, N, nhid, nfeat);
    // h1b = bf16(relu(spmm(h0q) + b1))
    spmm_csr256_relu<<<(N + 3) / 4, 256, 0, stream>>>(edges, rs, h0q, b1, h1b, N);

    // layer 2: h2q = fp8(h1b @ W2)
    dim3 g2((N + 127) / 128, nclass / 64);
    gemm_mfma<128, 64, 2, false><<<g2, 256, 0, stream>>>(h1b, W2T, h2q, N, nclass, nhid);
    // out = log_softmax(spmm(h2q) + b2)
    spmm_csr64_lsm<<<(N + 3) / 4, 256, 0, stream>>>(edges, rs, h2q, b2, out, N);
}

// Round 5
// 693.556 us; speedup vs baseline: 1.5296x; 1.0538x over previous
//
#include <hip/hip_runtime.h>
#include <math.h>

typedef short bf16x8 __attribute__((ext_vector_type(8)));
typedef float f32x4 __attribute__((ext_vector_type(4)));
typedef float f32x2 __attribute__((ext_vector_type(2)));

__device__ __forceinline__ float bf2f(unsigned short u) {
    return __uint_as_float(((unsigned)u) << 16);
}
__device__ __forceinline__ unsigned short f2bf(float f) {
    unsigned u = __float_as_uint(f);
    unsigned r = u + 0x7FFF + ((u >> 16) & 1);   // RNE
    return (unsigned short)(r >> 16);
}
__device__ __forceinline__ unsigned char f2fp8(float f) {
    const int p = __builtin_amdgcn_cvt_pk_fp8_f32(f, f, 0, false);
    return (unsigned char)(p & 0xff);
}
__device__ __forceinline__ unsigned cvt_pk_bf16(float a, float b) {
    unsigned r;
    asm("v_cvt_pk_bf16_f32 %0, %1, %2" : "=v"(r) : "v"(a), "v"(b));
    return r;
}

#define GLD_LDS16(gp, lp)                                                     \
    __builtin_amdgcn_global_load_lds(                                         \
        (const __attribute__((address_space(1))) void*)(gp),                  \
        (__attribute__((address_space(3))) void*)(lp), 16, 0, 0)

// C[M,Ncols] = A[M,K] @ BT[Ncols,K]^T, fp32 acc via MFMA.
// AF32: A is fp32 (converted to bf16 at fragment read); else A is bf16.
// OUTMODE: 0 = fp32, 1 = bf16, 2 = fp8 e4m3 (all row-major).
// 1D grid, col-fastest decode (rb = wg/ncb, cb = wg%ncb) + bijective
// XCD-chunked swizzle: col-sibling blocks (same A rows) get adjacent
// remapped IDs on the SAME XCD -> 2nd A-tile read is an L2 hit, so
// ncb>1 does not multiply A HBM traffic.
// BM=BN=128 keeps acc at 64 AGPR/wave (TM=TN=4) -> 2-3 blocks/CU
// (BN=256 was 128 AGPR -> >256 unified regs -> 1 wave/SIMD, 9% occupancy).
template <int BM, int BN, int OUTMODE, bool AF32>
__global__ __launch_bounds__(256) void gemm_mfma(const void* __restrict__ Av,
                                                 const unsigned short* __restrict__ BT,
                                                 void* __restrict__ Cv,
                                                 int M, int Ncols, int K, int ncb) {
    constexpr int WM = BM / 2, WN = BN / 2, TM = WM / 16, TN = WN / 16;
    constexpr int ABYTES = BM * 32 * (AF32 ? 4 : 2);
    __shared__ __align__(16) char smem[ABYTES + BN * 32 * 2];
    float* Alf = (float*)smem;
    unsigned short* Al = (unsigned short*)smem;
    unsigned short* Bl = (unsigned short*)(smem + ABYTES);
    const float* Af = (const float*)Av;
    const unsigned short* Ab = (const unsigned short*)Av;

    const int tid = threadIdx.x;
    const int w = tid >> 6, lane = tid & 63;
    const int wm = w >> 1, wn = w & 1;

    // bijective XCD swizzle (m204 variant; native dispatch round-robins XCDs)
    const int nwg = gridDim.x;
    const int orig = blockIdx.x;
    const int q8 = nwg >> 3, r8 = nwg & 7;
    const int xcd = orig & 7, jj = orig >> 3;
    const int wg = (xcd < r8 ? xcd * (q8 + 1) : r8 * (q8 + 1) + (xcd - r8) * q8) + jj;
    const int rb = wg / ncb, cb = wg - rb * ncb;
    const int row0 = rb * BM, col0 = cb * BN;
    const int q = lane >> 4, r = lane & 15;

    f32x4 acc[TM][TN];
    #pragma unroll
    for (int mt = 0; mt < TM; ++mt)
        #pragma unroll
        for (int nt = 0; nt < TN; ++nt) {
            f32x4 z = {0.f, 0.f, 0.f, 0.f};
            acc[mt][nt] = z;
        }

    for (int k0 = 0; k0 < K; k0 += 32) {
        __syncthreads();
        if (AF32) {
            // A tile: BM rows x 32 k fp32 (128 B/row = 8 x 16B chunks), XOR-swz
            #pragma unroll
            for (int i = 0; i < BM / 32; ++i) {
                const int idx = i * 256 + tid;
                const int arow = idx >> 3, pc = idx & 7;
                const int ch = pc ^ (arow & 7);
                int grow = row0 + arow;
                if (grow >= M) grow = M - 1;
                GLD_LDS16(Af + (size_t)grow * K + k0 + ch * 4,
                          Alf + (size_t)(i * 256 + w * 64) * 4);
            }
        } else {
            // A tile: BM rows x 32 k bf16 (64 B/row = 4 x 16B chunks), XOR-swz
            #pragma unroll
            for (int i = 0; i < BM / 64; ++i) {
                const int idx = i * 256 + tid;
                const int arow = idx >> 2, pc = idx & 3;
                const int ch = pc ^ ((arow >> 1) & 3);
                int grow = row0 + arow;
                if (grow >= M) grow = M - 1;
                GLD_LDS16(Ab + (size_t)grow * K + k0 + ch * 8,
                          Al + (size_t)(i * 256 + w * 64) * 8);
            }
        }
        // BT tile: BN rows x 32 k bf16, XOR-swz
        #pragma unroll
        for (int i = 0; i < BN / 64; ++i) {
            const int idx = i * 256 + tid;
            const int brow = idx >> 2, pc = idx & 3;
            const int ch = pc ^ ((brow >> 1) & 3);
            GLD_LDS16(BT + (size_t)(col0 + brow) * K + k0 + ch * 8,
                      Bl + (size_t)(i * 256 + w * 64) * 8);
        }
        asm volatile("s_waitcnt vmcnt(0)" ::: "memory");
        __syncthreads();

        bf16x8 af[TM], bfr[TN];
        #pragma unroll
        for (int mt = 0; mt < TM; ++mt) {
            const int rr = wm * WM + mt * 16 + r;
            if (AF32) {
                const int s8 = rr & 7;
                const f32x4 lo = *(const f32x4*)&Alf[rr * 32 + ((2 * q) ^ s8) * 4];
                const f32x4 hi = *(const f32x4*)&Alf[rr * 32 + ((2 * q + 1) ^ s8) * 4];
                union { bf16x8 v; unsigned u[4]; } cv;
                cv.u[0] = cvt_pk_bf16(lo.x, lo.y);
                cv.u[1] = cvt_pk_bf16(lo.z, lo.w);
                cv.u[2] = cvt_pk_bf16(hi.x, hi.y);
                cv.u[3] = cvt_pk_bf16(hi.z, hi.w);
                af[mt] = cv.v;
            } else {
                af[mt] = *(const bf16x8*)&Al[rr * 32 + (q ^ ((rr >> 1) & 3)) * 8];
            }
        }
        #pragma unroll
        for (int nt = 0; nt < TN; ++nt) {
            const int rr = wn * WN + nt * 16 + r;
            bfr[nt] = *(const bf16x8*)&Bl[rr * 32 + (q ^ ((rr >> 1) & 3)) * 8];
        }
        #pragma unroll
        for (int mt = 0; mt < TM; ++mt)
            #pragma unroll
            for (int nt = 0; nt < TN; ++nt)
                acc[mt][nt] = __builtin_amdgcn_mfma_f32_16x16x32_bf16(
                    af[mt], bfr[nt], acc[mt][nt], 0, 0, 0);
    }

    #pragma unroll
    for (int mt = 0; mt < TM; ++mt) {
        #pragma unroll
        for (int nt = 0; nt < TN; ++nt) {
            const int gcol = col0 + wn * WN + nt * 16 + r;
            #pragma unroll
            for (int j = 0; j < 4; ++j) {
                const int grow = row0 + wm * WM + mt * 16 + q * 4 + j;
                if (grow < M) {
                    if (OUTMODE == 2)
                        ((unsigned char*)Cv)[(size_t)grow * Ncols + gcol] = f2fp8(acc[mt][nt][j]);
                    else if (OUTMODE == 1)
                        ((unsigned short*)Cv)[(size_t)grow * Ncols + gcol] = f2bf(acc[mt][nt][j]);
                    else
                        ((float*)Cv)[(size_t)grow * Ncols + gcol] = acc[mt][nt][j];
                }
            }
        }
    }
}

// in: K x N fp32 -> out: N x K bf16 (transpose + cast); small matrices only.
__global__ __launch_bounds__(256) void transpose_cast(const float* __restrict__ in,
                                                      unsigned short* __restrict__ out,
                                                      int K, int N) {
    const int idx = blockIdx.x * 256 + threadIdx.x;
    if (idx < K * N) {
        const int k = idx / N, n = idx % N;
        out[(size_t)n * K + k] = f2bf(in[idx]);
    }
}

// ---- CSR build via bucketed 2-pass counting sort ----
// bucket = row >> 8 (256 rows/bucket).  NBMAX covers N up to 131072.
#define NBMAX 512
#define SB_CH 4096   // edges per block in scatter_bucket (16/thread)

__global__ __launch_bounds__(256) void bucket_hist(const int* __restrict__ rows,
                                                   int* __restrict__ bcnt, int E) {
    __shared__ int h[NBMAX];
    for (int i = threadIdx.x; i < NBMAX; i += 256) h[i] = 0;
    __syncthreads();
    for (long i = (long)blockIdx.x * 256 + threadIdx.x; i < E; i += (long)gridDim.x * 256)
        atomicAdd(&h[rows[i] >> 8], 1);
    __syncthreads();
    for (int i = threadIdx.x; i < NBMAX; i += 256)
        if (h[i]) atomicAdd(&bcnt[i], h[i]);
}

__global__ __launch_bounds__(512) void bucket_scan(const int* __restrict__ bcnt,
                                                   int* __restrict__ bstart, int nb) {
    __shared__ int s[NBMAX];
    const int t = threadIdx.x;
    const int v = (t < nb) ? bcnt[t] : 0;
    s[t] = v;
    __syncthreads();
    for (int o = 1; o < NBMAX; o <<= 1) {
        const int y = (t >= o) ? s[t - o] : 0;
        __syncthreads();
        s[t] += y;
        __syncthreads();
    }
    if (t < nb) bstart[t] = s[t] - v;
    if (t == nb - 1) bstart[nb] = s[t];
}

__global__ __launch_bounds__(256) void scatter_bucket(const int* __restrict__ rows,
                                                      const int* __restrict__ cols,
                                                      const float* __restrict__ vals,
                                                      const int* __restrict__ bstart,
                                                      int* __restrict__ bcursor,
                                                      int2* __restrict__ tmp, int E) {
    __shared__ int lcnt[NBMAX];
    __shared__ int lbase[NBMAX];
    const int t = threadIdx.x;
    const long c0 = (long)blockIdx.x * SB_CH;
    for (int i = t; i < NBMAX; i += 256) lcnt[i] = 0;
    __syncthreads();
    int rank[16], b[16];
    #pragma unroll
    for (int i = 0; i < 16; ++i) {
        const long e = c0 + i * 256 + t;
        if (e < E) {
            b[i] = rows[e] >> 8;
            rank[i] = atomicAdd(&lcnt[b[i]], 1);
        }
    }
    __syncthreads();
    for (int i = t; i < NBMAX; i += 256)
        lbase[i] = lcnt[i] ? atomicAdd(&bcursor[i], lcnt[i]) : 0;
    __syncthreads();
    #pragma unroll
    for (int i = 0; i < 16; ++i) {
        const long e = c0 + i * 256 + t;
        if (e < E) {
            const int r = rows[e];
            const int pos = bstart[b[i]] + lbase[b[i]] + rank[i];
            tmp[pos] = make_int2(((r & 255) << 17) | cols[e], __float_as_int(vals[e]));
        }
    }
}

__global__ __launch_bounds__(256) void bucket_to_csr(const int2* __restrict__ tmp,
                                                     const int* __restrict__ bstart,
                                                     int* __restrict__ rs,
                                                     int2* __restrict__ edges,
                                                     int N, int nb, int E) {
    __shared__ int rcnt[256];
    __shared__ int rsc[256];
    const int b = blockIdx.x;
    const int t = threadIdx.x;
    const int s = bstart[b], e = bstart[b + 1];
    rcnt[t] = 0;
    __syncthreads();
    for (int i = s + t; i < e; i += 256)
        atomicAdd(&rcnt[tmp[i].x >> 17], 1);
    __syncthreads();
    const int v = rcnt[t];
    rsc[t] = v;
    __syncthreads();
    for (int o = 1; o < 256; o <<= 1) {
        const int y = (t >= o) ? rsc[t - o] : 0;
        __syncthreads();
        rsc[t] += y;
        __syncthreads();
    }
    const int excl = rsc[t] - v;
    const int grow = b * 256 + t;
    if (grow < N) rs[grow] = s + excl;
    if (b == nb - 1 && t == 0) rs[N] = E;
    __syncthreads();
    rcnt[t] = s + excl;
    __syncthreads();
    for (int i = s + t; i < e; i += 256) {
        const int2 x = tmp[i];
        const int pos = atomicAdd(&rcnt[x.x >> 17], 1);
        edges[pos] = make_int2(x.x & 0x1FFFF, x.y);
    }
}

// ---- CSR spmm ----
// F=256 (fp8 X row-major), fused bias+relu, bf16 out.
// 8-edge unroll: edge records read as wave-uniform int4 pairs (scalar-load
// eligible via readfirstlane'd row), 8 independent 4B/lane gathers in flight.
__global__ __launch_bounds__(256) void spmm_csr256_relu(const int2* __restrict__ edges,
                                                        const int* __restrict__ rs,
                                                        const unsigned char* __restrict__ X,
                                                        const float* __restrict__ bias,
                                                        unsigned short* __restrict__ Y, int N) {
    const int row = __builtin_amdgcn_readfirstlane(blockIdx.x * 4 + (threadIdx.x >> 6));
    if (row >= N) return;
    const int lane = threadIdx.x & 63;
    const int s = rs[row], e = rs[row + 1];
    float a0 = 0.f, a1 = 0.f, a2 = 0.f, a3 = 0.f;
    int i = s;

#define SP256_ONE(col, vbits)                                                 \
    {                                                                         \
        const unsigned xw = ((const unsigned*)(X + (size_t)(col) * 256))[lane]; \
        const float v = __int_as_float(vbits);                                \
        const f32x2 l = __builtin_amdgcn_cvt_pk_f32_fp8(xw, false);           \
        const f32x2 h = __builtin_amdgcn_cvt_pk_f32_fp8(xw, true);            \
        a0 += v * l.x; a1 += v * l.y; a2 += v * h.x; a3 += v * h.y;           \
    }

    if ((i & 1) && i < e) {   // peel to 16B-align the int4 edge loads
        const int2 e0 = edges[i];
        SP256_ONE(e0.x, e0.y);
        ++i;
    }
    for (; i + 8 <= e; i += 8) {
        const int4 q0 = *(const int4*)(edges + i);
        const int4 q1 = *(const int4*)(edges + i + 2);
        const int4 q2 = *(const int4*)(edges + i + 4);
        const int4 q3 = *(const int4*)(edges + i + 6);
        const unsigned x0 = ((const unsigned*)(X + (size_t)q0.x * 256))[lane];
        const unsigned x1 = ((const unsigned*)(X + (size_t)q0.z * 256))[lane];
        const unsigned x2 = ((const unsigned*)(X + (size_t)q1.x * 256))[lane];
        const unsigned x3 = ((const unsigned*)(X + (size_t)q1.z * 256))[lane];
        const unsigned x4 = ((const unsigned*)(X + (size_t)q2.x * 256))[lane];
        const unsigned x5 = ((const unsigned*)(X + (size_t)q2.z * 256))[lane];
        const unsigned x6 = ((const unsigned*)(X + (size_t)q3.x * 256))[lane];
        const unsigned x7 = ((const unsigned*)(X + (size_t)q3.z * 256))[lane];
        const float v0 = __int_as_float(q0.y), v1 = __int_as_float(q0.w);
        const float v2 = __int_as_float(q1.y), v3 = __int_as_float(q1.w);
        const float v4 = __int_as_float(q2.y), v5 = __int_as_float(q2.w);
        const float v6 = __int_as_float(q3.y), v7 = __int_as_float(q3.w);
        const f32x2 l0 = __builtin_amdgcn_cvt_pk_f32_fp8(x0, false);
        const f32x2 h0 = __builtin_amdgcn_cvt_pk_f32_fp8(x0, true);
        const f32x2 l1 = __builtin_amdgcn_cvt_pk_f32_fp8(x1, false);
        const f32x2 h1 = __builtin_amdgcn_cvt_pk_f32_fp8(x1, true);
        const f32x2 l2 = __builtin_amdgcn_cvt_pk_f32_fp8(x2, false);
        const f32x2 h2 = __builtin_amdgcn_cvt_pk_f32_fp8(x2, true);
        const f32x2 l3 = __builtin_amdgcn_cvt_pk_f32_fp8(x3, false);
        const f32x2 h3 = __builtin_amdgcn_cvt_pk_f32_fp8(x3, true);
        const f32x2 l4 = __builtin_amdgcn_cvt_pk_f32_fp8(x4, false);
        const f32x2 h4 = __builtin_amdgcn_cvt_pk_f32_fp8(x4, true);
        const f32x2 l5 = __builtin_amdgcn_cvt_pk_f32_fp8(x5, false);
        const f32x2 h5 = __builtin_amdgcn_cvt_pk_f32_fp8(x5, true);
        const f32x2 l6 = __builtin_amdgcn_cvt_pk_f32_fp8(x6, false);
        const f32x2 h6 = __builtin_amdgcn_cvt_pk_f32_fp8(x6, true);
        const f32x2 l7 = __builtin_amdgcn_cvt_pk_f32_fp8(x7, false);
        const f32x2 h7 = __builtin_amdgcn_cvt_pk_f32_fp8(x7, true);
        a0 += v0 * l0.x + v1 * l1.x + v2 * l2.x + v3 * l3.x
            + v4 * l4.x + v5 * l5.x + v6 * l6.x + v7 * l7.x;
        a1 += v0 * l0.y + v1 * l1.y + v2 * l2.y + v3 * l3.y
            + v4 * l4.y + v5 * l5.y + v6 * l6.y + v7 * l7.y;
        a2 += v0 * h0.x + v1 * h1.x + v2 * h2.x + v3 * h3.x
            + v4 * h4.x + v5 * h5.x + v6 * h6.x + v7 * h7.x;
        a3 += v0 * h0.y + v1 * h1.y + v2 * h2.y + v3 * h3.y
            + v4 * h4.y + v5 * h5.y + v6 * h6.y + v7 * h7.y;
    }
    for (; i < e; ++i) {
        const int2 e0 = edges[i];
        SP256_ONE(e0.x, e0.y);
    }
#undef SP256_ONE

    const float4 bb = ((const float4*)bias)[lane];
    ushort4 o;
    o.x = f2bf(fmaxf(a0 + bb.x, 0.f));
    o.y = f2bf(fmaxf(a1 + bb.y, 0.f));
    o.z = f2bf(fmaxf(a2 + bb.z, 0.f));
    o.w = f2bf(fmaxf(a3 + bb.w, 0.f));
    ((ushort4*)(Y + (size_t)row * 256))[lane] = o;
}

// F=64 (fp8 X row-major), fused bias + log_softmax, fp32 out. 8-edge unroll.
__global__ __launch_bounds__(256) void spmm_csr64_lsm(const int2* __restrict__ edges,
                                                      const int* __restrict__ rs,
                                                      const unsigned char* __restrict__ X,
                                                      const float* __restrict__ bias,
                                                      float* __restrict__ out, int N) {
    const int row = __builtin_amdgcn_readfirstlane(blockIdx.x * 4 + (threadIdx.x >> 6));
    if (row >= N) return;
    const int lane = threadIdx.x & 63;
    const int s = rs[row], e = rs[row + 1];
    float acc = 0.f;
    int i = s;

#define SP64_ONE(col, vbits)                                                  \
    {                                                                         \
        const int u = X[(size_t)(col) * 64 + lane];                           \
        acc += __int_as_float(vbits) * __builtin_amdgcn_cvt_f32_fp8(u, 0);    \
    }

    if ((i & 1) && i < e) {
        const int2 e0 = edges[i];
        SP64_ONE(e0.x, e0.y);
        ++i;
    }
    for (; i + 8 <= e; i += 8) {
        const int4 q0 = *(const int4*)(edges + i);
        const int4 q1 = *(const int4*)(edges + i + 2);
        const int4 q2 = *(const int4*)(edges + i + 4);
        const int4 q3 = *(const int4*)(edges + i + 6);
        const int u0 = X[(size_t)q0.x * 64 + lane];
        const int u1 = X[(size_t)q0.z * 64 + lane];
        const int u2 = X[(size_t)q1.x * 64 + lane];
        const int u3 = X[(size_t)q1.z * 64 + lane];
        const int u4 = X[(size_t)q2.x * 64 + lane];
        const int u5 = X[(size_t)q2.z * 64 + lane];
        const int u6 = X[(size_t)q3.x * 64 + lane];
        const int u7 = X[(size_t)q3.z * 64 + lane];
        acc += __int_as_float(q0.y) * __builtin_amdgcn_cvt_f32_fp8(u0, 0)
             + __int_as_float(q0.w) * __builtin_amdgcn_cvt_f32_fp8(u1, 0)
             + __int_as_float(q1.y) * __builtin_amdgcn_cvt_f32_fp8(u2, 0)
             + __int_as_float(q1.w) * __builtin_amdgcn_cvt_f32_fp8(u3, 0)
             + __int_as_float(q2.y) * __builtin_amdgcn_cvt_f32_fp8(u4, 0)
             + __int_as_float(q2.w) * __builtin_amdgcn_cvt_f32_fp8(u5, 0)
             + __int_as_float(q3.y) * __builtin_amdgcn_cvt_f32_fp8(u6, 0)
             + __int_as_float(q3.w) * __builtin_amdgcn_cvt_f32_fp8(u7, 0);
    }
    for (; i < e; ++i) {
        const int2 e0 = edges[i];
        SP64_ONE(e0.x, e0.y);
    }
#undef SP64_ONE

    float v = acc + bias[lane];
    float m = v;
    #pragma unroll
    for (int o = 32; o; o >>= 1) m = fmaxf(m, __shfl_xor(m, o));
    const float ex = __expf(v - m);
    float ssum = ex;
    #pragma unroll
    for (int o = 32; o; o >>= 1) ssum += __shfl_xor(ssum, o);
    out[(size_t)row * 64 + lane] = v - m - __logf(ssum);
}

extern "C" void kernel_launch(void* const* d_in, const int* in_sizes, int n_in,
                              void* d_out, int out_size, void* d_ws, size_t ws_size,
                              hipStream_t stream) {
    const float* x    = (const float*)d_in[0];
    const int*   erow = (const int*)d_in[1];
    const int*   ecol = (const int*)d_in[2];
    const float* eval = (const float*)d_in[3];
    const float* W1   = (const float*)d_in[4];
    const float* b1   = (const float*)d_in[5];
    const float* W2   = (const float*)d_in[6];
    const float* b2   = (const float*)d_in[7];
    float* out = (float*)d_out;

    const int E      = in_sizes[1];
    const int nhid   = in_sizes[5];              // 256
    const int nclass = in_sizes[7];              // 64
    const int nfeat  = in_sizes[4] / nhid;       // 512
    const int N      = in_sizes[0] / nfeat;      // 100000

    // workspace layout (~104 MB, aliased regions noted)
    char* w = (char*)d_ws;
    unsigned short* h1b = (unsigned short*)w;     // [N][256] bf16 row-major (51.2 MB)
    int2* tmp = (int2*)w;                         // aliases h1b during CSR build (E*8)
    w += (size_t)N * nhid * 2;
    unsigned char* h0q = (unsigned char*)w;       // [N][256] fp8 row-major (25.6 MB)
    unsigned char* h2q = h0q;                     // aliases h0q after spmm1 ([N][64] fp8)
    w += (size_t)N * nhid;
    int2* edges = (int2*)w;                       w += (size_t)E * 8;
    int* rs = (int*)w;                            w += (size_t)(N + 1) * 4;
    int* bcnt = (int*)w;                          w += NBMAX * 4;
    int* bcursor = (int*)w;                       w += NBMAX * 4;
    int* bstart = (int*)w;                        w += (NBMAX + 1) * 4;
    unsigned short* W1T = (unsigned short*)w;     w += (size_t)nfeat * nhid * 2;
    unsigned short* W2T = (unsigned short*)w;     w += (size_t)nhid * nclass * 2;

    const int nb = (N + 255) >> 8;                // 391 buckets of 256 rows

    // CSR build: bucketed 2-pass counting sort (shared by both spmm layers)
    hipMemsetAsync(bcnt, 0, (size_t)2 * NBMAX * sizeof(int), stream);  // bcnt + bcursor
    bucket_hist<<<512, 256, 0, stream>>>(erow, bcnt, E);
    bucket_scan<<<1, NBMAX, 0, stream>>>(bcnt, bstart, nb);
    scatter_bucket<<<(E + SB_CH - 1) / SB_CH, 256, 0, stream>>>(erow, ecol, eval, bstart,
                                                                bcursor, tmp, E);
    bucket_to_csr<<<nb, 256, 0, stream>>>(tmp, bstart, rs, edges, N, nb, E);

    // weight transposes (tiny)
    transpose_cast<<<(nfeat * nhid + 255) / 256, 256, 0, stream>>>(W1, W1T, nfeat, nhid);
    transpose_cast<<<(nhid * nclass + 255) / 256, 256, 0, stream>>>(W2, W2T, nhid, nclass);

    // layer 1: h0q = fp8(x @ W1) — fp32 A staged directly into LDS (no cast pass)
    const int ncb1 = nhid / 128;                  // 2 col-blocks, col-fastest 1D grid
    const int ng1 = ((N + 127) / 128) * ncb1;
    gemm_mfma<128, 128, 2, true><<<ng1, 256, 0, stream>>>(x, W1T, h0q, N, nhid, nfeat, ncb1);
    // h1b = bf16(relu(spmm(h0q) + b1))
    spmm_csr256_relu<<<(N + 3) / 4, 256, 0, stream>>>(edges, rs, h0q, b1, h1b, N);

    // layer 2: h2q = fp8(h1b @ W2)
    const int ng2 = (N + 127) / 128;
    gemm_mfma<128, 64, 2, false><<<ng2, 256, 0, stream>>>(h1b, W2T, h2q, N, nclass, nhid, 1);
    // out = log_softmax(spmm(h2q) + b2)
    spmm_csr64_lsm<<<(N + 3) / 4, 256, 0, stream>>>(edges, rs, h2q, b2, out, N);
}

// Round 6
// 690.901 us; speedup vs baseline: 1.5354x; 1.0038x over previous
//
#include <hip/hip_runtime.h>
#include <math.h>

typedef short bf16x8 __attribute__((ext_vector_type(8)));
typedef float f32x4 __attribute__((ext_vector_type(4)));
typedef float f32x2 __attribute__((ext_vector_type(2)));

__device__ __forceinline__ float bf2f(unsigned short u) {
    return __uint_as_float(((unsigned)u) << 16);
}
__device__ __forceinline__ unsigned short f2bf(float f) {
    unsigned u = __float_as_uint(f);
    unsigned r = u + 0x7FFF + ((u >> 16) & 1);   // RNE
    return (unsigned short)(r >> 16);
}
__device__ __forceinline__ unsigned char f2fp8(float f) {
    const int p = __builtin_amdgcn_cvt_pk_fp8_f32(f, f, 0, false);
    return (unsigned char)(p & 0xff);
}
__device__ __forceinline__ unsigned cvt_pk_bf16(float a, float b) {
    unsigned r;
    asm("v_cvt_pk_bf16_f32 %0, %1, %2" : "=v"(r) : "v"(a), "v"(b));
    return r;
}

#define GLD_LDS16(gp, lp)                                                     \
    __builtin_amdgcn_global_load_lds(                                         \
        (const __attribute__((address_space(1))) void*)(gp),                  \
        (__attribute__((address_space(3))) void*)(lp), 16, 0, 0)

// C[M,Ncols] = A[M,K] @ BT[Ncols,K]^T, fp32 acc via MFMA.
// AMODE: 0 = bf16 A, 1 = fp32 A (cvt at frag read), 2 = fp8 e4m3 A (dequant
//        at frag read).  OUTMODE: 0 = fp32, 1 = bf16, 2 = fp8 (row-major).
// 2-phase double-buffered K-loop (catalog T3-minimum): STAGE(next) issued
// before COMPUTE(cur); single __syncthreads per tile (its implicit vmcnt(0)
// drain is the tile-ready guarantee).  LDS chunk-XOR swizzle on write-side
// source + read-side index kills power-of-2 row-stride bank conflicts.
// 1D grid, col-fastest decode + bijective XCD-chunked swizzle: col-sibling
// blocks land on the same XCD so the repeated A-tile read is an L2 hit.
template <int BM, int BN, int OUTMODE, int AMODE>
__global__ __launch_bounds__(256) void gemm_mfma(const void* __restrict__ Av,
                                                 const unsigned short* __restrict__ BT,
                                                 void* __restrict__ Cv,
                                                 int M, int Ncols, int K, int ncb) {
    constexpr int WM = BM / 2, WN = BN / 2, TM = WM / 16, TN = WN / 16;
    constexpr int ABYTES = BM * 32 * (AMODE == 1 ? 4 : (AMODE == 0 ? 2 : 1));
    constexpr int TILE = ABYTES + BN * 32 * 2;
    __shared__ __align__(16) char smem[2 * TILE];
    const float* Af = (const float*)Av;
    const unsigned short* Ab = (const unsigned short*)Av;
    const unsigned char* A8 = (const unsigned char*)Av;

    const int tid = threadIdx.x;
    const int w = tid >> 6, lane = tid & 63;
    const int wm = w >> 1, wn = w & 1;

    // bijective XCD swizzle (m204 variant)
    const int nwg = gridDim.x;
    const int orig = blockIdx.x;
    const int q8 = nwg >> 3, r8 = nwg & 7;
    const int xcd = orig & 7, jj = orig >> 3;
    const int wg = (xcd < r8 ? xcd * (q8 + 1) : r8 * (q8 + 1) + (xcd - r8) * q8) + jj;
    const int rb = wg / ncb, cb = wg - rb * ncb;
    const int row0 = rb * BM, col0 = cb * BN;
    const int q = lane >> 4, r = lane & 15;

    f32x4 acc[TM][TN];
    #pragma unroll
    for (int mt = 0; mt < TM; ++mt)
        #pragma unroll
        for (int nt = 0; nt < TN; ++nt) {
            f32x4 z = {0.f, 0.f, 0.f, 0.f};
            acc[mt][nt] = z;
        }

    auto STAGE = [&](int buf, int k0) {
        char* tb = smem + (size_t)buf * TILE;
        if constexpr (AMODE == 1) {
            float* Alf = (float*)tb;
            #pragma unroll
            for (int i = 0; i < BM / 32; ++i) {
                const int idx = i * 256 + tid;
                const int arow = idx >> 3, pc = idx & 7;
                const int ch = pc ^ (arow & 7);
                int grow = row0 + arow;
                if (grow >= M) grow = M - 1;
                GLD_LDS16(Af + (size_t)grow * K + k0 + ch * 4,
                          Alf + (size_t)(i * 256 + w * 64) * 4);
            }
        } else if constexpr (AMODE == 0) {
            unsigned short* Al = (unsigned short*)tb;
            #pragma unroll
            for (int i = 0; i < BM / 64; ++i) {
                const int idx = i * 256 + tid;
                const int arow = idx >> 2, pc = idx & 3;
                const int ch = pc ^ ((arow >> 1) & 3);
                int grow = row0 + arow;
                if (grow >= M) grow = M - 1;
                GLD_LDS16(Ab + (size_t)grow * K + k0 + ch * 8,
                          Al + (size_t)(i * 256 + w * 64) * 8);
            }
        } else {
            unsigned char* Al8 = (unsigned char*)tb;
            #pragma unroll
            for (int i = 0; i < BM / 128; ++i) {
                const int idx = i * 256 + tid;
                const int arow = idx >> 1, pc = idx & 1;
                const int ch = pc ^ (arow & 1);
                int grow = row0 + arow;
                if (grow >= M) grow = M - 1;
                GLD_LDS16(A8 + (size_t)grow * K + k0 + ch * 16,
                          Al8 + (size_t)(i * 256 + w * 64) * 16);
            }
        }
        unsigned short* Bl = (unsigned short*)(tb + ABYTES);
        #pragma unroll
        for (int i = 0; i < BN / 64; ++i) {
            const int idx = i * 256 + tid;
            const int brow = idx >> 2, pc = idx & 3;
            const int ch = pc ^ ((brow >> 1) & 3);
            GLD_LDS16(BT + (size_t)(col0 + brow) * K + k0 + ch * 8,
                      Bl + (size_t)(i * 256 + w * 64) * 8);
        }
    };

    auto COMPUTE = [&](int buf) {
        char* tb = smem + (size_t)buf * TILE;
        const unsigned short* Bl = (const unsigned short*)(tb + ABYTES);
        bf16x8 af[TM], bfr[TN];
        #pragma unroll
        for (int mt = 0; mt < TM; ++mt) {
            const int rr = wm * WM + mt * 16 + r;
            if constexpr (AMODE == 1) {
                const float* Alf = (const float*)tb;
                const int s8 = rr & 7;
                const f32x4 lo = *(const f32x4*)&Alf[rr * 32 + ((2 * q) ^ s8) * 4];
                const f32x4 hi = *(const f32x4*)&Alf[rr * 32 + ((2 * q + 1) ^ s8) * 4];
                union { bf16x8 v; unsigned u[4]; } cv;
                cv.u[0] = cvt_pk_bf16(lo.x, lo.y);
                cv.u[1] = cvt_pk_bf16(lo.z, lo.w);
                cv.u[2] = cvt_pk_bf16(hi.x, hi.y);
                cv.u[3] = cvt_pk_bf16(hi.z, hi.w);
                af[mt] = cv.v;
            } else if constexpr (AMODE == 0) {
                const unsigned short* Al = (const unsigned short*)tb;
                af[mt] = *(const bf16x8*)&Al[rr * 32 + (q ^ ((rr >> 1) & 3)) * 8];
            } else {
                const unsigned char* Al8 = (const unsigned char*)tb;
                const uint2 wv = *(const uint2*)(Al8 + rr * 32 +
                                                 (((q >> 1) ^ (rr & 1)) << 4) + ((q & 1) << 3));
                const f32x2 p0 = __builtin_amdgcn_cvt_pk_f32_fp8(wv.x, false);
                const f32x2 p1 = __builtin_amdgcn_cvt_pk_f32_fp8(wv.x, true);
                const f32x2 p2 = __builtin_amdgcn_cvt_pk_f32_fp8(wv.y, false);
                const f32x2 p3 = __builtin_amdgcn_cvt_pk_f32_fp8(wv.y, true);
                union { bf16x8 v; unsigned u[4]; } cv;
                cv.u[0] = cvt_pk_bf16(p0.x, p0.y);
                cv.u[1] = cvt_pk_bf16(p1.x, p1.y);
                cv.u[2] = cvt_pk_bf16(p2.x, p2.y);
                cv.u[3] = cvt_pk_bf16(p3.x, p3.y);
                af[mt] = cv.v;
            }
        }
        #pragma unroll
        for (int nt = 0; nt < TN; ++nt) {
            const int rr = wn * WN + nt * 16 + r;
            bfr[nt] = *(const bf16x8*)&Bl[rr * 32 + (q ^ ((rr >> 1) & 3)) * 8];
        }
        #pragma unroll
        for (int mt = 0; mt < TM; ++mt)
            #pragma unroll
            for (int nt = 0; nt < TN; ++nt)
                acc[mt][nt] = __builtin_amdgcn_mfma_f32_16x16x32_bf16(
                    af[mt], bfr[nt], acc[mt][nt], 0, 0, 0);
    };

    const int nkt = K >> 5;
    STAGE(0, 0);
    __syncthreads();                 // drains vmcnt(0): tile 0 ready
    int cur = 0;
    for (int kt = 0; kt < nkt; ++kt) {
        if (kt + 1 < nkt) STAGE(cur ^ 1, (kt + 1) << 5);   // issue-early
        COMPUTE(cur);                // overlaps with in-flight loads
        __syncthreads();             // drains vmcnt: next tile ready; reads done
        cur ^= 1;
    }

    #pragma unroll
    for (int mt = 0; mt < TM; ++mt) {
        #pragma unroll
        for (int nt = 0; nt < TN; ++nt) {
            const int gcol = col0 + wn * WN + nt * 16 + r;
            #pragma unroll
            for (int j = 0; j < 4; ++j) {
                const int grow = row0 + wm * WM + mt * 16 + q * 4 + j;
                if (grow < M) {
                    if (OUTMODE == 2)
                        ((unsigned char*)Cv)[(size_t)grow * Ncols + gcol] = f2fp8(acc[mt][nt][j]);
                    else if (OUTMODE == 1)
                        ((unsigned short*)Cv)[(size_t)grow * Ncols + gcol] = f2bf(acc[mt][nt][j]);
                    else
                        ((float*)Cv)[(size_t)grow * Ncols + gcol] = acc[mt][nt][j];
                }
            }
        }
    }
}

// both weight transposes (K1 x N1 and K2 x N2 fp32 -> N x K bf16) in one launch
__global__ __launch_bounds__(256) void transpose_cast2(const float* __restrict__ in1,
                                                       unsigned short* __restrict__ out1,
                                                       int K1, int N1,
                                                       const float* __restrict__ in2,
                                                       unsigned short* __restrict__ out2,
                                                       int K2, int N2) {
    int idx = blockIdx.x * 256 + threadIdx.x;
    const int t1 = K1 * N1;
    if (idx < t1) {
        const int k = idx / N1, n = idx % N1;
        out1[(size_t)n * K1 + k] = f2bf(in1[idx]);
    } else {
        idx -= t1;
        if (idx < K2 * N2) {
            const int k = idx / N2, n = idx % N2;
            out2[(size_t)n * K2 + k] = f2bf(in2[idx]);
        }
    }
}

// ---- CSR build via bucketed 2-pass counting sort ----
// bucket = row >> 8 (256 rows/bucket).  NBMAX covers N up to 131072.
#define NBMAX 512
#define SB_CH 4096   // edges per block in scatter_bucket (16/thread)

__global__ __launch_bounds__(256) void bucket_hist(const int* __restrict__ rows,
                                                   int* __restrict__ bcnt, int E) {
    __shared__ int h[NBMAX];
    for (int i = threadIdx.x; i < NBMAX; i += 256) h[i] = 0;
    __syncthreads();
    for (long i = (long)blockIdx.x * 256 + threadIdx.x; i < E; i += (long)gridDim.x * 256)
        atomicAdd(&h[rows[i] >> 8], 1);
    __syncthreads();
    for (int i = threadIdx.x; i < NBMAX; i += 256)
        if (h[i]) atomicAdd(&bcnt[i], h[i]);
}

__global__ __launch_bounds__(512) void bucket_scan(const int* __restrict__ bcnt,
                                                   int* __restrict__ bstart, int nb) {
    __shared__ int s[NBMAX];
    const int t = threadIdx.x;
    const int v = (t < nb) ? bcnt[t] : 0;
    s[t] = v;
    __syncthreads();
    for (int o = 1; o < NBMAX; o <<= 1) {
        const int y = (t >= o) ? s[t - o] : 0;
        __syncthreads();
        s[t] += y;
        __syncthreads();
    }
    if (t < nb) bstart[t] = s[t] - v;
    if (t == nb - 1) bstart[nb] = s[t];
}

__global__ __launch_bounds__(256) void scatter_bucket(const int* __restrict__ rows,
                                                      const int* __restrict__ cols,
                                                      const float* __restrict__ vals,
                                                      const int* __restrict__ bstart,
                                                      int* __restrict__ bcursor,
                                                      int2* __restrict__ tmp, int E) {
    __shared__ int lcnt[NBMAX];
    __shared__ int lbase[NBMAX];
    const int t = threadIdx.x;
    const long c0 = (long)blockIdx.x * SB_CH;
    for (int i = t; i < NBMAX; i += 256) lcnt[i] = 0;
    __syncthreads();
    int rank[16], b[16];
    #pragma unroll
    for (int i = 0; i < 16; ++i) {
        const long e = c0 + i * 256 + t;
        if (e < E) {
            b[i] = rows[e] >> 8;
            rank[i] = atomicAdd(&lcnt[b[i]], 1);
        }
    }
    __syncthreads();
    for (int i = t; i < NBMAX; i += 256)
        lbase[i] = lcnt[i] ? atomicAdd(&bcursor[i], lcnt[i]) : 0;
    __syncthreads();
    #pragma unroll
    for (int i = 0; i < 16; ++i) {
        const long e = c0 + i * 256 + t;
        if (e < E) {
            const int r = rows[e];
            const int pos = bstart[b[i]] + lbase[b[i]] + rank[i];
            tmp[pos] = make_int2(((r & 255) << 17) | cols[e], __float_as_int(vals[e]));
        }
    }
}

__global__ __launch_bounds__(256) void bucket_to_csr(const int2* __restrict__ tmp,
                                                     const int* __restrict__ bstart,
                                                     int* __restrict__ rs,
                                                     int2* __restrict__ edges,
                                                     int N, int nb, int E) {
    __shared__ int rcnt[256];
    __shared__ int rsc[256];
    const int b = blockIdx.x;
    const int t = threadIdx.x;
    const int s = bstart[b], e = bstart[b + 1];
    rcnt[t] = 0;
    __syncthreads();
    for (int i = s + t; i < e; i += 256)
        atomicAdd(&rcnt[tmp[i].x >> 17], 1);
    __syncthreads();
    const int v = rcnt[t];
    rsc[t] = v;
    __syncthreads();
    for (int o = 1; o < 256; o <<= 1) {
        const int y = (t >= o) ? rsc[t - o] : 0;
        __syncthreads();
        rsc[t] += y;
        __syncthreads();
    }
    const int excl = rsc[t] - v;
    const int grow = b * 256 + t;
    if (grow < N) rs[grow] = s + excl;
    if (b == nb - 1 && t == 0) rs[N] = E;
    __syncthreads();
    rcnt[t] = s + excl;
    __syncthreads();
    for (int i = s + t; i < e; i += 256) {
        const int2 x = tmp[i];
        const int pos = atomicAdd(&rcnt[x.x >> 17], 1);
        edges[pos] = make_int2(x.x & 0x1FFFF, x.y);
    }
}

// ---- CSR spmm ----
// F=256 (fp8 X row-major), fused bias+relu, fp8 out (feeds gemm2's fp8-A).
// 8-edge unroll: edge records read as wave-uniform int4 pairs, 8 independent
// 4B/lane gathers in flight.
__global__ __launch_bounds__(256) void spmm_csr256_relu(const int2* __restrict__ edges,
                                                        const int* __restrict__ rs,
                                                        const unsigned char* __restrict__ X,
                                                        const float* __restrict__ bias,
                                                        unsigned char* __restrict__ Y, int N) {
    const int row = __builtin_amdgcn_readfirstlane(blockIdx.x * 4 + (threadIdx.x >> 6));
    if (row >= N) return;
    const int lane = threadIdx.x & 63;
    const int s = rs[row], e = rs[row + 1];
    float a0 = 0.f, a1 = 0.f, a2 = 0.f, a3 = 0.f;
    int i = s;

#define SP256_ONE(col, vbits)                                                 \
    {                                                                         \
        const unsigned xw = ((const unsigned*)(X + (size_t)(col) * 256))[lane]; \
        const float v = __int_as_float(vbits);                                \
        const f32x2 l = __builtin_amdgcn_cvt_pk_f32_fp8(xw, false);           \
        const f32x2 h = __builtin_amdgcn_cvt_pk_f32_fp8(xw, true);            \
        a0 += v * l.x; a1 += v * l.y; a2 += v * h.x; a3 += v * h.y;           \
    }

    if ((i & 1) && i < e) {   // peel to 16B-align the int4 edge loads
        const int2 e0 = edges[i];
        SP256_ONE(e0.x, e0.y);
        ++i;
    }
    for (; i + 8 <= e; i += 8) {
        const int4 q0 = *(const int4*)(edges + i);
        const int4 q1 = *(const int4*)(edges + i + 2);
        const int4 q2 = *(const int4*)(edges + i + 4);
        const int4 q3 = *(const int4*)(edges + i + 6);
        const unsigned x0 = ((const unsigned*)(X + (size_t)q0.x * 256))[lane];
        const unsigned x1 = ((const unsigned*)(X + (size_t)q0.z * 256))[lane];
        const unsigned x2 = ((const unsigned*)(X + (size_t)q1.x * 256))[lane];
        const unsigned x3 = ((const unsigned*)(X + (size_t)q1.z * 256))[lane];
        const unsigned x4 = ((const unsigned*)(X + (size_t)q2.x * 256))[lane];
        const unsigned x5 = ((const unsigned*)(X + (size_t)q2.z * 256))[lane];
        const unsigned x6 = ((const unsigned*)(X + (size_t)q3.x * 256))[lane];
        const unsigned x7 = ((const unsigned*)(X + (size_t)q3.z * 256))[lane];
        const float v0 = __int_as_float(q0.y), v1 = __int_as_float(q0.w);
        const float v2 = __int_as_float(q1.y), v3 = __int_as_float(q1.w);
        const float v4 = __int_as_float(q2.y), v5 = __int_as_float(q2.w);
        const float v6 = __int_as_float(q3.y), v7 = __int_as_float(q3.w);
        const f32x2 l0 = __builtin_amdgcn_cvt_pk_f32_fp8(x0, false);
        const f32x2 h0 = __builtin_amdgcn_cvt_pk_f32_fp8(x0, true);
        const f32x2 l1 = __builtin_amdgcn_cvt_pk_f32_fp8(x1, false);
        const f32x2 h1 = __builtin_amdgcn_cvt_pk_f32_fp8(x1, true);
        const f32x2 l2 = __builtin_amdgcn_cvt_pk_f32_fp8(x2, false);
        const f32x2 h2 = __builtin_amdgcn_cvt_pk_f32_fp8(x2, true);
        const f32x2 l3 = __builtin_amdgcn_cvt_pk_f32_fp8(x3, false);
        const f32x2 h3 = __builtin_amdgcn_cvt_pk_f32_fp8(x3, true);
        const f32x2 l4 = __builtin_amdgcn_cvt_pk_f32_fp8(x4, false);
        const f32x2 h4 = __builtin_amdgcn_cvt_pk_f32_fp8(x4, true);
        const f32x2 l5 = __builtin_amdgcn_cvt_pk_f32_fp8(x5, false);
        const f32x2 h5 = __builtin_amdgcn_cvt_pk_f32_fp8(x5, true);
        const f32x2 l6 = __builtin_amdgcn_cvt_pk_f32_fp8(x6, false);
        const f32x2 h6 = __builtin_amdgcn_cvt_pk_f32_fp8(x6, true);
        const f32x2 l7 = __builtin_amdgcn_cvt_pk_f32_fp8(x7, false);
        const f32x2 h7 = __builtin_amdgcn_cvt_pk_f32_fp8(x7, true);
        a0 += v0 * l0.x + v1 * l1.x + v2 * l2.x + v3 * l3.x
            + v4 * l4.x + v5 * l5.x + v6 * l6.x + v7 * l7.x;
        a1 += v0 * l0.y + v1 * l1.y + v2 * l2.y + v3 * l3.y
            + v4 * l4.y + v5 * l5.y + v6 * l6.y + v7 * l7.y;
        a2 += v0 * h0.x + v1 * h1.x + v2 * h2.x + v3 * h3.x
            + v4 * h4.x + v5 * h5.x + v6 * h6.x + v7 * h7.x;
        a3 += v0 * h0.y + v1 * h1.y + v2 * h2.y + v3 * h3.y
            + v4 * h4.y + v5 * h5.y + v6 * h6.y + v7 * h7.y;
    }
    for (; i < e; ++i) {
        const int2 e0 = edges[i];
        SP256_ONE(e0.x, e0.y);
    }
#undef SP256_ONE

    const float4 bb = ((const float4*)bias)[lane];
    unsigned wo = __builtin_amdgcn_cvt_pk_fp8_f32(fmaxf(a0 + bb.x, 0.f),
                                                  fmaxf(a1 + bb.y, 0.f), 0, false);
    wo = __builtin_amdgcn_cvt_pk_fp8_f32(fmaxf(a2 + bb.z, 0.f),
                                         fmaxf(a3 + bb.w, 0.f), wo, true);
    ((unsigned*)(Y + (size_t)row * 256))[lane] = wo;
}

// F=64 (fp8 X row-major), fused bias + log_softmax, fp32 out. 8-edge unroll.
__global__ __launch_bounds__(256) void spmm_csr64_lsm(const int2* __restrict__ edges,
                                                      const int* __restrict__ rs,
                                                      const unsigned char* __restrict__ X,
                                                      const float* __restrict__ bias,
                                                      float* __restrict__ out, int N) {
    const int row = __builtin_amdgcn_readfirstlane(blockIdx.x * 4 + (threadIdx.x >> 6));
    if (row >= N) return;
    const int lane = threadIdx.x & 63;
    const int s = rs[row], e = rs[row + 1];
    float acc = 0.f;
    int i = s;

#define SP64_ONE(col, vbits)                                                  \
    {                                                                         \
        const int u = X[(size_t)(col) * 64 + lane];                           \
        acc += __int_as_float(vbits) * __builtin_amdgcn_cvt_f32_fp8(u, 0);    \
    }

    if ((i & 1) && i < e) {
        const int2 e0 = edges[i];
        SP64_ONE(e0.x, e0.y);
        ++i;
    }
    for (; i + 8 <= e; i += 8) {
        const int4 q0 = *(const int4*)(edges + i);
        const int4 q1 = *(const int4*)(edges + i + 2);
        const int4 q2 = *(const int4*)(edges + i + 4);
        const int4 q3 = *(const int4*)(edges + i + 6);
        const int u0 = X[(size_t)q0.x * 64 + lane];
        const int u1 = X[(size_t)q0.z * 64 + lane];
        const int u2 = X[(size_t)q1.x * 64 + lane];
        const int u3 = X[(size_t)q1.z * 64 + lane];
        const int u4 = X[(size_t)q2.x * 64 + lane];
        const int u5 = X[(size_t)q2.z * 64 + lane];
        const int u6 = X[(size_t)q3.x * 64 + lane];
        const int u7 = X[(size_t)q3.z * 64 + lane];
        acc += __int_as_float(q0.y) * __builtin_amdgcn_cvt_f32_fp8(u0, 0)
             + __int_as_float(q0.w) * __builtin_amdgcn_cvt_f32_fp8(u1, 0)
             + __int_as_float(q1.y) * __builtin_amdgcn_cvt_f32_fp8(u2, 0)
             + __int_as_float(q1.w) * __builtin_amdgcn_cvt_f32_fp8(u3, 0)
             + __int_as_float(q2.y) * __builtin_amdgcn_cvt_f32_fp8(u4, 0)
             + __int_as_float(q2.w) * __builtin_amdgcn_cvt_f32_fp8(u5, 0)
             + __int_as_float(q3.y) * __builtin_amdgcn_cvt_f32_fp8(u6, 0)
             + __int_as_float(q3.w) * __builtin_amdgcn_cvt_f32_fp8(u7, 0);
    }
    for (; i < e; ++i) {
        const int2 e0 = edges[i];
        SP64_ONE(e0.x, e0.y);
    }
#undef SP64_ONE

    float v = acc + bias[lane];
    float m = v;
    #pragma unroll
    for (int o = 32; o; o >>= 1) m = fmaxf(m, __shfl_xor(m, o));
    const float ex = __expf(v - m);
    float ssum = ex;
    #pragma unroll
    for (int o = 32; o; o >>= 1) ssum += __shfl_xor(ssum, o);
    out[(size_t)row * 64 + lane] = v - m - __logf(ssum);
}

extern "C" void kernel_launch(void* const* d_in, const int* in_sizes, int n_in,
                              void* d_out, int out_size, void* d_ws, size_t ws_size,
                              hipStream_t stream) {
    const float* x    = (const float*)d_in[0];
    const int*   erow = (const int*)d_in[1];
    const int*   ecol = (const int*)d_in[2];
    const float* eval = (const float*)d_in[3];
    const float* W1   = (const float*)d_in[4];
    const float* b1   = (const float*)d_in[5];
    const float* W2   = (const float*)d_in[6];
    const float* b2   = (const float*)d_in[7];
    float* out = (float*)d_out;

    const int E      = in_sizes[1];
    const int nhid   = in_sizes[5];              // 256
    const int nclass = in_sizes[7];              // 64
    const int nfeat  = in_sizes[4] / nhid;       // 512
    const int N      = in_sizes[0] / nfeat;      // 100000

    // workspace layout (~78 MB, aliased regions noted)
    char* w = (char*)d_ws;
    unsigned char* h1q = (unsigned char*)w;       // [N][256] fp8 (25.6 MB)
    int2* tmp = (int2*)w;                         // aliases h1q during CSR build (E*8)
    w += (size_t)N * nhid;
    unsigned char* h0q = (unsigned char*)w;       // [N][256] fp8 (25.6 MB)
    unsigned char* h2q = h0q;                     // aliases h0q after spmm1 ([N][64] fp8)
    w += (size_t)N * nhid;
    int2* edges = (int2*)w;                       w += (size_t)E * 8;
    int* rs = (int*)w;                            w += (size_t)(N + 1) * 4;
    int* bcnt = (int*)w;                          w += NBMAX * 4;
    int* bcursor = (int*)w;                       w += NBMAX * 4;
    int* bstart = (int*)w;                        w += (NBMAX + 1) * 4;
    unsigned short* W1T = (unsigned short*)w;     w += (size_t)nfeat * nhid * 2;
    unsigned short* W2T = (unsigned short*)w;     w += (size_t)nhid * nclass * 2;

    const int nb = (N + 255) >> 8;                // 391 buckets of 256 rows

    // CSR build: bucketed 2-pass counting sort (shared by both spmm layers)
    hipMemsetAsync(bcnt, 0, (size_t)2 * NBMAX * sizeof(int), stream);  // bcnt + bcursor
    bucket_hist<<<512, 256, 0, stream>>>(erow, bcnt, E);
    bucket_scan<<<1, NBMAX, 0, stream>>>(bcnt, bstart, nb);
    scatter_bucket<<<(E + SB_CH - 1) / SB_CH, 256, 0, stream>>>(erow, ecol, eval, bstart,
                                                                bcursor, tmp, E);
    bucket_to_csr<<<nb, 256, 0, stream>>>(tmp, bstart, rs, edges, N, nb, E);

    // both weight transposes, one launch
    const int tc_total = nfeat * nhid + nhid * nclass;
    transpose_cast2<<<(tc_total + 255) / 256, 256, 0, stream>>>(W1, W1T, nfeat, nhid,
                                                                W2, W2T, nhid, nclass);

    // layer 1: h0q = fp8(x @ W1) — fp32 A staged directly into LDS (no cast pass)
    const int ncb1 = nhid / 128;                  // 2 col-blocks, col-fastest 1D grid
    const int ng1 = ((N + 127) / 128) * ncb1;
    gemm_mfma<128, 128, 2, 1><<<ng1, 256, 0, stream>>>(x, W1T, h0q, N, nhid, nfeat, ncb1);
    // h1q = fp8(relu(spmm(h0q) + b1))
    spmm_csr256_relu<<<(N + 3) / 4, 256, 0, stream>>>(edges, rs, h0q, b1, h1q, N);

    // layer 2: h2q = fp8(h1q @ W2), fp8 A dequantized at fragment read
    const int ng2 = (N + 127) / 128;
    gemm_mfma<128, 64, 2, 2><<<ng2, 256, 0, stream>>>(h1q, W2T, h2q, N, nclass, nhid, 1);
    // out = log_softmax(spmm(h2q) + b2)
    spmm_csr64_lsm<<<(N + 3) / 4, 256, 0, stream>>>(edges, rs, h2q, b2, out, N);
}

// Round 7
// 685.108 us; speedup vs baseline: 1.5484x; 1.0085x over previous
//
#include <hip/hip_runtime.h>
#include <math.h>

typedef short bf16x8 __attribute__((ext_vector_type(8)));
typedef float f32x4 __attribute__((ext_vector_type(4)));
typedef float f32x2 __attribute__((ext_vector_type(2)));

__device__ __forceinline__ float bf2f(unsigned short u) {
    return __uint_as_float(((unsigned)u) << 16);
}
__device__ __forceinline__ unsigned short f2bf(float f) {
    unsigned u = __float_as_uint(f);
    unsigned r = u + 0x7FFF + ((u >> 16) & 1);   // RNE
    return (unsigned short)(r >> 16);
}
__device__ __forceinline__ unsigned char f2fp8(float f) {
    const int p = __builtin_amdgcn_cvt_pk_fp8_f32(f, f, 0, false);
    return (unsigned char)(p & 0xff);
}
__device__ __forceinline__ unsigned cvt_pk_bf16(float a, float b) {
    unsigned r;
    asm("v_cvt_pk_bf16_f32 %0, %1, %2" : "=v"(r) : "v"(a), "v"(b));
    return r;
}

template <int NN>
__device__ __forceinline__ void wait_vmcnt() {
    if constexpr (NN == 0) asm volatile("s_waitcnt vmcnt(0)" ::: "memory");
    else if constexpr (NN == 2) asm volatile("s_waitcnt vmcnt(2)" ::: "memory");
    else if constexpr (NN == 3) asm volatile("s_waitcnt vmcnt(3)" ::: "memory");
    else if constexpr (NN == 4) asm volatile("s_waitcnt vmcnt(4)" ::: "memory");
    else if constexpr (NN == 5) asm volatile("s_waitcnt vmcnt(5)" ::: "memory");
    else if constexpr (NN == 6) asm volatile("s_waitcnt vmcnt(6)" ::: "memory");
    else if constexpr (NN == 8) asm volatile("s_waitcnt vmcnt(8)" ::: "memory");
    else asm volatile("s_waitcnt vmcnt(0)" ::: "memory");
}

#define GLD_LDS16(gp, lp)                                                     \
    __builtin_amdgcn_global_load_lds(                                         \
        (const __attribute__((address_space(1))) void*)(gp),                  \
        (__attribute__((address_space(3))) void*)(lp), 16, 0, 0)

// C[M,Ncols] = A[M,K] @ BT[Ncols,K]^T, fp32 acc via MFMA.
// AMODE: 0 = bf16 A, 1 = fp32 A (cvt at frag read), 2 = fp8 e4m3 A (dequant
//        at frag read).  OUTMODE: 0 = fp32, 1 = bf16, 2 = fp8 (row-major).
// K-loop: 2-deep counted-vmcnt pipeline (catalog T4) — raw s_barrier, wait
// vmcnt(L) keeps the NEXT tile's L loads in flight across barriers; never
// drains to 0 in the loop.  Per-wave vmcnt(L)+barrier => all waves' tile-t
// LDS writes landed; lgkmcnt(0)+barrier => safe buffer overwrite.
// LDS chunk-XOR swizzle kills power-of-2 row-stride bank conflicts.
// 1D grid, col-fastest decode + bijective XCD-chunked swizzle (col-sibling
// blocks share an XCD -> repeated A-tile read is an L2 hit).
template <int BM, int BN, int OUTMODE, int AMODE>
__global__ __launch_bounds__(256) void gemm_mfma(const void* __restrict__ Av,
                                                 const unsigned short* __restrict__ BT,
                                                 void* __restrict__ Cv,
                                                 int M, int Ncols, int K, int ncb) {
    constexpr int WM = BM / 2, WN = BN / 2, TM = WM / 16, TN = WN / 16;
    constexpr int ABYTES = BM * 32 * (AMODE == 1 ? 4 : (AMODE == 0 ? 2 : 1));
    constexpr int TILE = ABYTES + BN * 32 * 2;
    constexpr int LPT = (AMODE == 1 ? BM / 32 : (AMODE == 0 ? BM / 64 : BM / 128)) + BN / 64;
    __shared__ __align__(16) char smem[2 * TILE];
    const float* Af = (const float*)Av;
    const unsigned short* Ab = (const unsigned short*)Av;
    const unsigned char* A8 = (const unsigned char*)Av;

    const int tid = threadIdx.x;
    const int w = tid >> 6, lane = tid & 63;
    const int wm = w >> 1, wn = w & 1;

    // bijective XCD swizzle (m204 variant)
    const int nwg = gridDim.x;
    const int orig = blockIdx.x;
    const int q8 = nwg >> 3, r8 = nwg & 7;
    const int xcd = orig & 7, jj = orig >> 3;
    const int wg = (xcd < r8 ? xcd * (q8 + 1) : r8 * (q8 + 1) + (xcd - r8) * q8) + jj;
    const int rb = wg / ncb, cb = wg - rb * ncb;
    const int row0 = rb * BM, col0 = cb * BN;
    const int q = lane >> 4, r = lane & 15;

    f32x4 acc[TM][TN];
    #pragma unroll
    for (int mt = 0; mt < TM; ++mt)
        #pragma unroll
        for (int nt = 0; nt < TN; ++nt) {
            f32x4 z = {0.f, 0.f, 0.f, 0.f};
            acc[mt][nt] = z;
        }

    auto STAGE = [&](int buf, int k0) {
        char* tb = smem + (size_t)buf * TILE;
        if constexpr (AMODE == 1) {
            float* Alf = (float*)tb;
            #pragma unroll
            for (int i = 0; i < BM / 32; ++i) {
                const int idx = i * 256 + tid;
                const int arow = idx >> 3, pc = idx & 7;
                const int ch = pc ^ (arow & 7);
                int grow = row0 + arow;
                if (grow >= M) grow = M - 1;
                GLD_LDS16(Af + (size_t)grow * K + k0 + ch * 4,
                          Alf + (size_t)(i * 256 + w * 64) * 4);
            }
        } else if constexpr (AMODE == 0) {
            unsigned short* Al = (unsigned short*)tb;
            #pragma unroll
            for (int i = 0; i < BM / 64; ++i) {
                const int idx = i * 256 + tid;
                const int arow = idx >> 2, pc = idx & 3;
                const int ch = pc ^ ((arow >> 1) & 3);
                int grow = row0 + arow;
                if (grow >= M) grow = M - 1;
                GLD_LDS16(Ab + (size_t)grow * K + k0 + ch * 8,
                          Al + (size_t)(i * 256 + w * 64) * 8);
            }
        } else {
            unsigned char* Al8 = (unsigned char*)tb;
            #pragma unroll
            for (int i = 0; i < BM / 128; ++i) {
                const int idx = i * 256 + tid;
                const int arow = idx >> 1, pc = idx & 1;
                const int ch = pc ^ (arow & 1);
                int grow = row0 + arow;
                if (grow >= M) grow = M - 1;
                GLD_LDS16(A8 + (size_t)grow * K + k0 + ch * 16,
                          Al8 + (size_t)(i * 256 + w * 64) * 16);
            }
        }
        unsigned short* Bl = (unsigned short*)(tb + ABYTES);
        #pragma unroll
        for (int i = 0; i < BN / 64; ++i) {
            const int idx = i * 256 + tid;
            const int brow = idx >> 2, pc = idx & 3;
            const int ch = pc ^ ((brow >> 1) & 3);
            GLD_LDS16(BT + (size_t)(col0 + brow) * K + k0 + ch * 8,
                      Bl + (size_t)(i * 256 + w * 64) * 8);
        }
    };

    auto COMPUTE = [&](int buf) {
        char* tb = smem + (size_t)buf * TILE;
        const unsigned short* Bl = (const unsigned short*)(tb + ABYTES);
        bf16x8 af[TM], bfr[TN];
        #pragma unroll
        for (int mt = 0; mt < TM; ++mt) {
            const int rr = wm * WM + mt * 16 + r;
            if constexpr (AMODE == 1) {
                const float* Alf = (const float*)tb;
                const int s8 = rr & 7;
                const f32x4 lo = *(const f32x4*)&Alf[rr * 32 + ((2 * q) ^ s8) * 4];
                const f32x4 hi = *(const f32x4*)&Alf[rr * 32 + ((2 * q + 1) ^ s8) * 4];
                union { bf16x8 v; unsigned u[4]; } cv;
                cv.u[0] = cvt_pk_bf16(lo.x, lo.y);
                cv.u[1] = cvt_pk_bf16(lo.z, lo.w);
                cv.u[2] = cvt_pk_bf16(hi.x, hi.y);
                cv.u[3] = cvt_pk_bf16(hi.z, hi.w);
                af[mt] = cv.v;
            } else if constexpr (AMODE == 0) {
                const unsigned short* Al = (const unsigned short*)tb;
                af[mt] = *(const bf16x8*)&Al[rr * 32 + (q ^ ((rr >> 1) & 3)) * 8];
            } else {
                const unsigned char* Al8 = (const unsigned char*)tb;
                const uint2 wv = *(const uint2*)(Al8 + rr * 32 +
                                                 (((q >> 1) ^ (rr & 1)) << 4) + ((q & 1) << 3));
                const f32x2 p0 = __builtin_amdgcn_cvt_pk_f32_fp8(wv.x, false);
                const f32x2 p1 = __builtin_amdgcn_cvt_pk_f32_fp8(wv.x, true);
                const f32x2 p2 = __builtin_amdgcn_cvt_pk_f32_fp8(wv.y, false);
                const f32x2 p3 = __builtin_amdgcn_cvt_pk_f32_fp8(wv.y, true);
                union { bf16x8 v; unsigned u[4]; } cv;
                cv.u[0] = cvt_pk_bf16(p0.x, p0.y);
                cv.u[1] = cvt_pk_bf16(p1.x, p1.y);
                cv.u[2] = cvt_pk_bf16(p2.x, p2.y);
                cv.u[3] = cvt_pk_bf16(p3.x, p3.y);
                af[mt] = cv.v;
            }
        }
        #pragma unroll
        for (int nt = 0; nt < TN; ++nt) {
            const int rr = wn * WN + nt * 16 + r;
            bfr[nt] = *(const bf16x8*)&Bl[rr * 32 + (q ^ ((rr >> 1) & 3)) * 8];
        }
        #pragma unroll
        for (int mt = 0; mt < TM; ++mt)
            #pragma unroll
            for (int nt = 0; nt < TN; ++nt)
                acc[mt][nt] = __builtin_amdgcn_mfma_f32_16x16x32_bf16(
                    af[mt], bfr[nt], acc[mt][nt], 0, 0, 0);
    };

    const int nkt = K >> 5;
    STAGE(0, 0);
    if (nkt > 1) STAGE(1, 32);
    for (int kt = 0; kt < nkt; ++kt) {
        const int buf = kt & 1;
        if (kt + 1 < nkt) wait_vmcnt<LPT>();   // tile kt done; kt+1 stays in flight
        else wait_vmcnt<0>();                  // last tile: drain
        __builtin_amdgcn_s_barrier();          // all waves: tile kt ready
        COMPUTE(buf);
        asm volatile("s_waitcnt lgkmcnt(0)" ::: "memory");  // my LDS reads returned
        __builtin_amdgcn_s_barrier();          // all waves done reading buf
        if (kt + 2 < nkt) STAGE(buf, (kt + 2) << 5);        // refill to 2L in flight
    }

    #pragma unroll
    for (int mt = 0; mt < TM; ++mt) {
        #pragma unroll
        for (int nt = 0; nt < TN; ++nt) {
            const int gcol = col0 + wn * WN + nt * 16 + r;
            #pragma unroll
            for (int j = 0; j < 4; ++j) {
                const int grow = row0 + wm * WM + mt * 16 + q * 4 + j;
                if (grow < M) {
                    if (OUTMODE == 2)
                        ((unsigned char*)Cv)[(size_t)grow * Ncols + gcol] = f2fp8(acc[mt][nt][j]);
                    else if (OUTMODE == 1)
                        ((unsigned short*)Cv)[(size_t)grow * Ncols + gcol] = f2bf(acc[mt][nt][j]);
                    else
                        ((float*)Cv)[(size_t)grow * Ncols + gcol] = acc[mt][nt][j];
                }
            }
        }
    }
}

// ---- CSR build via bucketed 2-pass counting sort ----
// bucket = row >> 8 (256 rows/bucket).  NBMAX covers N up to 131072.
#define NBMAX 512
#define SB_CH 4096   // edges per block in scatter_bucket (16/thread)
#define HIST_BLOCKS 512

// fused: blocks [0,HIST_BLOCKS) do the LDS-privatized bucket histogram;
// blocks beyond do both weight transposes (independent work, same stream slot).
__global__ __launch_bounds__(256) void hist_and_transpose(
        const int* __restrict__ rows, int* __restrict__ bcnt, int E,
        const float* __restrict__ in1, unsigned short* __restrict__ out1, int K1, int N1,
        const float* __restrict__ in2, unsigned short* __restrict__ out2, int K2, int N2) {
    if (blockIdx.x < HIST_BLOCKS) {
        __shared__ int h[NBMAX];
        for (int i = threadIdx.x; i < NBMAX; i += 256) h[i] = 0;
        __syncthreads();
        for (long i = (long)blockIdx.x * 256 + threadIdx.x; i < E;
             i += (long)HIST_BLOCKS * 256)
            atomicAdd(&h[rows[i] >> 8], 1);
        __syncthreads();
        for (int i = threadIdx.x; i < NBMAX; i += 256)
            if (h[i]) atomicAdd(&bcnt[i], h[i]);
    } else {
        int idx = (blockIdx.x - HIST_BLOCKS) * 256 + threadIdx.x;
        const int t1 = K1 * N1;
        if (idx < t1) {
            const int k = idx / N1, n = idx % N1;
            out1[(size_t)n * K1 + k] = f2bf(in1[idx]);
        } else {
            idx -= t1;
            if (idx < K2 * N2) {
                const int k = idx / N2, n = idx % N2;
                out2[(size_t)n * K2 + k] = f2bf(in2[idx]);
            }
        }
    }
}

__global__ __launch_bounds__(512) void bucket_scan(const int* __restrict__ bcnt,
                                                   int* __restrict__ bstart, int nb) {
    __shared__ int s[NBMAX];
    const int t = threadIdx.x;
    const int v = (t < nb) ? bcnt[t] : 0;
    s[t] = v;
    __syncthreads();
    for (int o = 1; o < NBMAX; o <<= 1) {
        const int y = (t >= o) ? s[t - o] : 0;
        __syncthreads();
        s[t] += y;
        __syncthreads();
    }
    if (t < nb) bstart[t] = s[t] - v;
    if (t == nb - 1) bstart[nb] = s[t];
}

__global__ __launch_bounds__(256) void scatter_bucket(const int* __restrict__ rows,
                                                      const int* __restrict__ cols,
                                                      const float* __restrict__ vals,
                                                      const int* __restrict__ bstart,
                                                      int* __restrict__ bcursor,
                                                      int2* __restrict__ tmp, int E) {
    __shared__ int lcnt[NBMAX];
    __shared__ int lbase[NBMAX];
    const int t = threadIdx.x;
    const long c0 = (long)blockIdx.x * SB_CH;
    for (int i = t; i < NBMAX; i += 256) lcnt[i] = 0;
    __syncthreads();
    int rank[16], b[16];
    #pragma unroll
    for (int i = 0; i < 16; ++i) {
        const long e = c0 + i * 256 + t;
        if (e < E) {
            b[i] = rows[e] >> 8;
            rank[i] = atomicAdd(&lcnt[b[i]], 1);
        }
    }
    __syncthreads();
    for (int i = t; i < NBMAX; i += 256)
        lbase[i] = lcnt[i] ? atomicAdd(&bcursor[i], lcnt[i]) : 0;
    __syncthreads();
    #pragma unroll
    for (int i = 0; i < 16; ++i) {
        const long e = c0 + i * 256 + t;
        if (e < E) {
            const int r = rows[e];
            const int pos = bstart[b[i]] + lbase[b[i]] + rank[i];
            tmp[pos] = make_int2(((r & 255) << 17) | cols[e], __float_as_int(vals[e]));
        }
    }
}

__global__ __launch_bounds__(256) void bucket_to_csr(const int2* __restrict__ tmp,
                                                     const int* __restrict__ bstart,
                                                     int* __restrict__ rs,
                                                     int2* __restrict__ edges,
                                                     int N, int nb, int E) {
    __shared__ int rcnt[256];
    __shared__ int rsc[256];
    const int b = blockIdx.x;
    const int t = threadIdx.x;
    const int s = bstart[b], e = bstart[b + 1];
    rcnt[t] = 0;
    __syncthreads();
    for (int i = s + t; i < e; i += 256)
        atomicAdd(&rcnt[tmp[i].x >> 17], 1);
    __syncthreads();
    const int v = rcnt[t];
    rsc[t] = v;
    __syncthreads();
    for (int o = 1; o < 256; o <<= 1) {
        const int y = (t >= o) ? rsc[t - o] : 0;
        __syncthreads();
        rsc[t] += y;
        __syncthreads();
    }
    const int excl = rsc[t] - v;
    const int grow = b * 256 + t;
    if (grow < N) rs[grow] = s + excl;
    if (b == nb - 1 && t == 0) rs[N] = E;
    __syncthreads();
    rcnt[t] = s + excl;
    __syncthreads();
    for (int i = s + t; i < e; i += 256) {
        const int2 x = tmp[i];
        const int pos = atomicAdd(&rcnt[x.x >> 17], 1);
        edges[pos] = make_int2(x.x & 0x1FFFF, x.y);
    }
}

// ---- CSR spmm ----
// F=256 (fp8 X row-major), fused bias+relu, fp8 out (feeds gemm2's fp8-A).
// 8-edge unroll: edge records read as wave-uniform int4 pairs, 8 independent
// 4B/lane gathers in flight.
__global__ __launch_bounds__(256) void spmm_csr256_relu(const int2* __restrict__ edges,
                                                        const int* __restrict__ rs,
                                                        const unsigned char* __restrict__ X,
                                                        const float* __restrict__ bias,
                                                        unsigned char* __restrict__ Y, int N) {
    const int row = __builtin_amdgcn_readfirstlane(blockIdx.x * 4 + (threadIdx.x >> 6));
    if (row >= N) return;
    const int lane = threadIdx.x & 63;
    const int s = rs[row], e = rs[row + 1];
    float a0 = 0.f, a1 = 0.f, a2 = 0.f, a3 = 0.f;
    int i = s;

#define SP256_ONE(col, vbits)                                                 \
    {                                                                         \
        const unsigned xw = ((const unsigned*)(X + (size_t)(col) * 256))[lane]; \
        const float v = __int_as_float(vbits);                                \
        const f32x2 l = __builtin_amdgcn_cvt_pk_f32_fp8(xw, false);           \
        const f32x2 h = __builtin_amdgcn_cvt_pk_f32_fp8(xw, true);            \
        a0 += v * l.x; a1 += v * l.y; a2 += v * h.x; a3 += v * h.y;           \
    }

    if ((i & 1) && i < e) {   // peel to 16B-align the int4 edge loads
        const int2 e0 = edges[i];
        SP256_ONE(e0.x, e0.y);
        ++i;
    }
    for (; i + 8 <= e; i += 8) {
        const int4 q0 = *(const int4*)(edges + i);
        const int4 q1 = *(const int4*)(edges + i + 2);
        const int4 q2 = *(const int4*)(edges + i + 4);
        const int4 q3 = *(const int4*)(edges + i + 6);
        const unsigned x0 = ((const unsigned*)(X + (size_t)q0.x * 256))[lane];
        const unsigned x1 = ((const unsigned*)(X + (size_t)q0.z * 256))[lane];
        const unsigned x2 = ((const unsigned*)(X + (size_t)q1.x * 256))[lane];
        const unsigned x3 = ((const unsigned*)(X + (size_t)q1.z * 256))[lane];
        const unsigned x4 = ((const unsigned*)(X + (size_t)q2.x * 256))[lane];
        const unsigned x5 = ((const unsigned*)(X + (size_t)q2.z * 256))[lane];
        const unsigned x6 = ((const unsigned*)(X + (size_t)q3.x * 256))[lane];
        const unsigned x7 = ((const unsigned*)(X + (size_t)q3.z * 256))[lane];
        const float v0 = __int_as_float(q0.y), v1 = __int_as_float(q0.w);
        const float v2 = __int_as_float(q1.y), v3 = __int_as_float(q1.w);
        const float v4 = __int_as_float(q2.y), v5 = __int_as_float(q2.w);
        const float v6 = __int_as_float(q3.y), v7 = __int_as_float(q3.w);
        const f32x2 l0 = __builtin_amdgcn_cvt_pk_f32_fp8(x0, false);
        const f32x2 h0 = __builtin_amdgcn_cvt_pk_f32_fp8(x0, true);
        const f32x2 l1 = __builtin_amdgcn_cvt_pk_f32_fp8(x1, false);
        const f32x2 h1 = __builtin_amdgcn_cvt_pk_f32_fp8(x1, true);
        const f32x2 l2 = __builtin_amdgcn_cvt_pk_f32_fp8(x2, false);
        const f32x2 h2 = __builtin_amdgcn_cvt_pk_f32_fp8(x2, true);
        const f32x2 l3 = __builtin_amdgcn_cvt_pk_f32_fp8(x3, false);
        const f32x2 h3 = __builtin_amdgcn_cvt_pk_f32_fp8(x3, true);
        const f32x2 l4 = __builtin_amdgcn_cvt_pk_f32_fp8(x4, false);
        const f32x2 h4 = __builtin_amdgcn_cvt_pk_f32_fp8(x4, true);
        const f32x2 l5 = __builtin_amdgcn_cvt_pk_f32_fp8(x5, false);
        const f32x2 h5 = __builtin_amdgcn_cvt_pk_f32_fp8(x5, true);
        const f32x2 l6 = __builtin_amdgcn_cvt_pk_f32_fp8(x6, false);
        const f32x2 h6 = __builtin_amdgcn_cvt_pk_f32_fp8(x6, true);
        const f32x2 l7 = __builtin_amdgcn_cvt_pk_f32_fp8(x7, false);
        const f32x2 h7 = __builtin_amdgcn_cvt_pk_f32_fp8(x7, true);
        a0 += v0 * l0.x + v1 * l1.x + v2 * l2.x + v3 * l3.x
            + v4 * l4.x + v5 * l5.x + v6 * l6.x + v7 * l7.x;
        a1 += v0 * l0.y + v1 * l1.y + v2 * l2.y + v3 * l3.y
            + v4 * l4.y + v5 * l5.y + v6 * l6.y + v7 * l7.y;
        a2 += v0 * h0.x + v1 * h1.x + v2 * h2.x + v3 * h3.x
            + v4 * h4.x + v5 * h5.x + v6 * h6.x + v7 * h7.x;
        a3 += v0 * h0.y + v1 * h1.y + v2 * h2.y + v3 * h3.y
            + v4 * h4.y + v5 * h5.y + v6 * h6.y + v7 * h7.y;
    }
    for (; i < e; ++i) {
        const int2 e0 = edges[i];
        SP256_ONE(e0.x, e0.y);
    }
#undef SP256_ONE

    const float4 bb = ((const float4*)bias)[lane];
    unsigned wo = __builtin_amdgcn_cvt_pk_fp8_f32(fmaxf(a0 + bb.x, 0.f),
                                                  fmaxf(a1 + bb.y, 0.f), 0, false);
    wo = __builtin_amdgcn_cvt_pk_fp8_f32(fmaxf(a2 + bb.z, 0.f),
                                         fmaxf(a3 + bb.w, 0.f), wo, true);
    ((unsigned*)(Y + (size_t)row * 256))[lane] = wo;
}

// F=64 (fp8 X row-major), fused bias + log_softmax, fp32 out. 8-edge unroll.
__global__ __launch_bounds__(256) void spmm_csr64_lsm(const int2* __restrict__ edges,
                                                      const int* __restrict__ rs,
                                                      const unsigned char* __restrict__ X,
                                                      const float* __restrict__ bias,
                                                      float* __restrict__ out, int N) {
    const int row = __builtin_amdgcn_readfirstlane(blockIdx.x * 4 + (threadIdx.x >> 6));
    if (row >= N) return;
    const int lane = threadIdx.x & 63;
    const int s = rs[row], e = rs[row + 1];
    float acc = 0.f;
    int i = s;

#define SP64_ONE(col, vbits)                                                  \
    {                                                                         \
        const int u = X[(size_t)(col) * 64 + lane];                           \
        acc += __int_as_float(vbits) * __builtin_amdgcn_cvt_f32_fp8(u, 0);    \
    }

    if ((i & 1) && i < e) {
        const int2 e0 = edges[i];
        SP64_ONE(e0.x, e0.y);
        ++i;
    }
    for (; i + 8 <= e; i += 8) {
        const int4 q0 = *(const int4*)(edges + i);
        const int4 q1 = *(const int4*)(edges + i + 2);
        const int4 q2 = *(const int4*)(edges + i + 4);
        const int4 q3 = *(const int4*)(edges + i + 6);
        const int u0 = X[(size_t)q0.x * 64 + lane];
        const int u1 = X[(size_t)q0.z * 64 + lane];
        const int u2 = X[(size_t)q1.x * 64 + lane];
        const int u3 = X[(size_t)q1.z * 64 + lane];
        const int u4 = X[(size_t)q2.x * 64 + lane];
        const int u5 = X[(size_t)q2.z * 64 + lane];
        const int u6 = X[(size_t)q3.x * 64 + lane];
        const int u7 = X[(size_t)q3.z * 64 + lane];
        acc += __int_as_float(q0.y) * __builtin_amdgcn_cvt_f32_fp8(u0, 0)
             + __int_as_float(q0.w) * __builtin_amdgcn_cvt_f32_fp8(u1, 0)
             + __int_as_float(q1.y) * __builtin_amdgcn_cvt_f32_fp8(u2, 0)
             + __int_as_float(q1.w) * __builtin_amdgcn_cvt_f32_fp8(u3, 0)
             + __int_as_float(q2.y) * __builtin_amdgcn_cvt_f32_fp8(u4, 0)
             + __int_as_float(q2.w) * __builtin_amdgcn_cvt_f32_fp8(u5, 0)
             + __int_as_float(q3.y) * __builtin_amdgcn_cvt_f32_fp8(u6, 0)
             + __int_as_float(q3.w) * __builtin_amdgcn_cvt_f32_fp8(u7, 0);
    }
    for (; i < e; ++i) {
        const int2 e0 = edges[i];
        SP64_ONE(e0.x, e0.y);
    }
#undef SP64_ONE

    float v = acc + bias[lane];
    float m = v;
    #pragma unroll
    for (int o = 32; o; o >>= 1) m = fmaxf(m, __shfl_xor(m, o));
    const float ex = __expf(v - m);
    float ssum = ex;
    #pragma unroll
    for (int o = 32; o; o >>= 1) ssum += __shfl_xor(ssum, o);
    out[(size_t)row * 64 + lane] = v - m - __logf(ssum);
}

extern "C" void kernel_launch(void* const* d_in, const int* in_sizes, int n_in,
                              void* d_out, int out_size, void* d_ws, size_t ws_size,
                              hipStream_t stream) {
    const float* x    = (const float*)d_in[0];
    const int*   erow = (const int*)d_in[1];
    const int*   ecol = (const int*)d_in[2];
    const float* eval = (const float*)d_in[3];
    const float* W1   = (const float*)d_in[4];
    const float* b1   = (const float*)d_in[5];
    const float* W2   = (const float*)d_in[6];
    const float* b2   = (const float*)d_in[7];
    float* out = (float*)d_out;

    const int E      = in_sizes[1];
    const int nhid   = in_sizes[5];              // 256
    const int nclass = in_sizes[7];              // 64
    const int nfeat  = in_sizes[4] / nhid;       // 512
    const int N      = in_sizes[0] / nfeat;      // 100000

    // workspace layout (~78 MB, aliased regions noted)
    char* w = (char*)d_ws;
    unsigned char* h1q = (unsigned char*)w;       // [N][256] fp8 (25.6 MB)
    int2* tmp = (int2*)w;                         // aliases h1q during CSR build (E*8)
    w += (size_t)N * nhid;
    unsigned char* h0q = (unsigned char*)w;       // [N][256] fp8 (25.6 MB)
    unsigned char* h2q = h0q;                     // aliases h0q after spmm1 ([N][64] fp8)
    w += (size_t)N * nhid;
    int2* edges = (int2*)w;                       w += (size_t)E * 8;
    int* rs = (int*)w;                            w += (size_t)(N + 1) * 4;
    int* bcnt = (int*)w;                          w += NBMAX * 4;
    int* bcursor = (int*)w;                       w += NBMAX * 4;
    int* bstart = (int*)w;                        w += (NBMAX + 1) * 4;
    unsigned short* W1T = (unsigned short*)w;     w += (size_t)nfeat * nhid * 2;
    unsigned short* W2T = (unsigned short*)w;     w += (size_t)nhid * nclass * 2;

    const int nb = (N + 255) >> 8;                // 391 buckets of 256 rows

    // CSR build (shared by both spmm layers) + weight transposes fused in
    hipMemsetAsync(bcnt, 0, (size_t)2 * NBMAX * sizeof(int), stream);  // bcnt + bcursor
    const int tc_total = nfeat * nhid + nhid * nclass;
    const int ht_grid = HIST_BLOCKS + (tc_total + 255) / 256;
    hist_and_transpose<<<ht_grid, 256, 0, stream>>>(erow, bcnt, E,
                                                    W1, W1T, nfeat, nhid,
                                                    W2, W2T, nhid, nclass);
    bucket_scan<<<1, NBMAX, 0, stream>>>(bcnt, bstart, nb);
    scatter_bucket<<<(E + SB_CH - 1) / SB_CH, 256, 0, stream>>>(erow, ecol, eval, bstart,
                                                                bcursor, tmp, E);
    bucket_to_csr<<<nb, 256, 0, stream>>>(tmp, bstart, rs, edges, N, nb, E);

    // layer 1: h0q = fp8(x @ W1) — fp32 A staged directly into LDS (no cast pass)
    const int ncb1 = nhid / 128;                  // 2 col-blocks, col-fastest 1D grid
    const int ng1 = ((N + 127) / 128) * ncb1;
    gemm_mfma<128, 128, 2, 1><<<ng1, 256, 0, stream>>>(x, W1T, h0q, N, nhid, nfeat, ncb1);
    // h1q = fp8(relu(spmm(h0q) + b1))
    spmm_csr256_relu<<<(N + 3) / 4, 256, 0, stream>>>(edges, rs, h0q, b1, h1q, N);

    // layer 2: h2q = fp8(h1q @ W2), fp8 A dequantized at fragment read
    const int ng2 = (N + 127) / 128;
    gemm_mfma<128, 64, 2, 2><<<ng2, 256, 0, stream>>>(h1q, W2T, h2q, N, nclass, nhid, 1);
    // out = log_softmax(spmm(h2q) + b2)
    spmm_csr64_lsm<<<(N + 3) / 4, 256, 0, stream>>>(edges, rs, h2q, b2, out, N);
}

// Round 8
// 644.887 us; speedup vs baseline: 1.6450x; 1.0624x over previous
//
#include <hip/hip_runtime.h>
#include <math.h>

typedef short bf16x8 __attribute__((ext_vector_type(8)));
typedef float f32x4 __attribute__((ext_vector_type(4)));
typedef float f32x2 __attribute__((ext_vector_type(2)));

#define NBMAX 512
#define SB_CH 4096
#define HIST_BLOCKS 512

__device__ __forceinline__ float bf2f(unsigned short u) {
    return __uint_as_float(((unsigned)u) << 16);
}
__device__ __forceinline__ unsigned short f2bf(float f) {
    unsigned u = __float_as_uint(f);
    unsigned r = u + 0x7FFF + ((u >> 16) & 1);   // RNE
    return (unsigned short)(r >> 16);
}
__device__ __forceinline__ unsigned char f2fp8(float f) {
    const int p = __builtin_amdgcn_cvt_pk_fp8_f32(f, f, 0, false);
    return (unsigned char)(p & 0xff);
}
__device__ __forceinline__ unsigned cvt_pk_bf16(float a, float b) {
    unsigned r;
    asm("v_cvt_pk_bf16_f32 %0, %1, %2" : "=v"(r) : "v"(a), "v"(b));
    return r;
}

template <int NN>
__device__ __forceinline__ void wait_vmcnt() {
    if constexpr (NN == 0) asm volatile("s_waitcnt vmcnt(0)" ::: "memory");
    else if constexpr (NN == 2) asm volatile("s_waitcnt vmcnt(2)" ::: "memory");
    else if constexpr (NN == 3) asm volatile("s_waitcnt vmcnt(3)" ::: "memory");
    else if constexpr (NN == 4) asm volatile("s_waitcnt vmcnt(4)" ::: "memory");
    else if constexpr (NN == 5) asm volatile("s_waitcnt vmcnt(5)" ::: "memory");
    else if constexpr (NN == 6) asm volatile("s_waitcnt vmcnt(6)" ::: "memory");
    else if constexpr (NN == 8) asm volatile("s_waitcnt vmcnt(8)" ::: "memory");
    else asm volatile("s_waitcnt vmcnt(0)" ::: "memory");
}

#define GLD_LDS16(gp, lp)                                                     \
    __builtin_amdgcn_global_load_lds(                                         \
        (const __attribute__((address_space(1))) void*)(gp),                  \
        (__attribute__((address_space(3))) void*)(lp), 16, 0, 0)

// ---- GEMM body (device fn so it can be grid-fused with CSR-build work) ----
// C[M,Ncols] = A[M,K] @ BT[Ncols,K]^T, fp32 acc via MFMA.
// AMODE: 1 = fp32 A (cvt at frag read), 2 = fp8 e4m3 A (dequant at frag read).
// OUTMODE: 2 = fp8 row-major.  2-deep counted-vmcnt K-pipeline (T4): raw
// s_barrier, wait vmcnt(LPT) keeps next tile's loads in flight; never drains
// to 0 in the loop.  LDS chunk-XOR swizzle kills bank conflicts.  1D grid,
// col-fastest decode + bijective XCD-chunked swizzle over the FULL grid
// (orig/nwg passed in so split halves across two launches stay bijective).
template <int BM, int BN, int OUTMODE, int AMODE>
__device__ __forceinline__ void gemm_body(char* smem, int orig, int nwg,
                                          const void* __restrict__ Av,
                                          const unsigned short* __restrict__ BT,
                                          void* __restrict__ Cv,
                                          int M, int Ncols, int K, int ncb) {
    constexpr int WM = BM / 2, WN = BN / 2, TM = WM / 16, TN = WN / 16;
    constexpr int ABYTES = BM * 32 * (AMODE == 1 ? 4 : (AMODE == 0 ? 2 : 1));
    constexpr int TILE = ABYTES + BN * 32 * 2;
    constexpr int LPT = (AMODE == 1 ? BM / 32 : (AMODE == 0 ? BM / 64 : BM / 128)) + BN / 64;
    const float* Af = (const float*)Av;
    const unsigned short* Ab = (const unsigned short*)Av;
    const unsigned char* A8 = (const unsigned char*)Av;

    const int tid = threadIdx.x;
    const int w = tid >> 6, lane = tid & 63;
    const int wm = w >> 1, wn = w & 1;

    // bijective XCD swizzle (m204 variant) over the full logical grid
    const int q8 = nwg >> 3, r8 = nwg & 7;
    const int xcd = orig & 7, jj = orig >> 3;
    const int wg = (xcd < r8 ? xcd * (q8 + 1) : r8 * (q8 + 1) + (xcd - r8) * q8) + jj;
    const int rb = wg / ncb, cb = wg - rb * ncb;
    const int row0 = rb * BM, col0 = cb * BN;
    const int q = lane >> 4, r = lane & 15;

    f32x4 acc[TM][TN];
    #pragma unroll
    for (int mt = 0; mt < TM; ++mt)
        #pragma unroll
        for (int nt = 0; nt < TN; ++nt) {
            f32x4 z = {0.f, 0.f, 0.f, 0.f};
            acc[mt][nt] = z;
        }

    auto STAGE = [&](int buf, int k0) {
        char* tb = smem + (size_t)buf * TILE;
        if constexpr (AMODE == 1) {
            float* Alf = (float*)tb;
            #pragma unroll
            for (int i = 0; i < BM / 32; ++i) {
                const int idx = i * 256 + tid;
                const int arow = idx >> 3, pc = idx & 7;
                const int ch = pc ^ (arow & 7);
                int grow = row0 + arow;
                if (grow >= M) grow = M - 1;
                GLD_LDS16(Af + (size_t)grow * K + k0 + ch * 4,
                          Alf + (size_t)(i * 256 + w * 64) * 4);
            }
        } else if constexpr (AMODE == 0) {
            unsigned short* Al = (unsigned short*)tb;
            #pragma unroll
            for (int i = 0; i < BM / 64; ++i) {
                const int idx = i * 256 + tid;
                const int arow = idx >> 2, pc = idx & 3;
                const int ch = pc ^ ((arow >> 1) & 3);
                int grow = row0 + arow;
                if (grow >= M) grow = M - 1;
                GLD_LDS16(Ab + (size_t)grow * K + k0 + ch * 8,
                          Al + (size_t)(i * 256 + w * 64) * 8);
            }
        } else {
            unsigned char* Al8 = (unsigned char*)tb;
            #pragma unroll
            for (int i = 0; i < BM / 128; ++i) {
                const int idx = i * 256 + tid;
                const int arow = idx >> 1, pc = idx & 1;
                const int ch = pc ^ (arow & 1);
                int grow = row0 + arow;
                if (grow >= M) grow = M - 1;
                GLD_LDS16(A8 + (size_t)grow * K + k0 + ch * 16,
                          Al8 + (size_t)(i * 256 + w * 64) * 16);
            }
        }
        unsigned short* Bl = (unsigned short*)(tb + ABYTES);
        #pragma unroll
        for (int i = 0; i < BN / 64; ++i) {
            const int idx = i * 256 + tid;
            const int brow = idx >> 2, pc = idx & 3;
            const int ch = pc ^ ((brow >> 1) & 3);
            GLD_LDS16(BT + (size_t)(col0 + brow) * K + k0 + ch * 8,
                      Bl + (size_t)(i * 256 + w * 64) * 8);
        }
    };

    auto COMPUTE = [&](int buf) {
        char* tb = smem + (size_t)buf * TILE;
        const unsigned short* Bl = (const unsigned short*)(tb + ABYTES);
        bf16x8 af[TM], bfr[TN];
        #pragma unroll
        for (int mt = 0; mt < TM; ++mt) {
            const int rr = wm * WM + mt * 16 + r;
            if constexpr (AMODE == 1) {
                const float* Alf = (const float*)tb;
                const int s8 = rr & 7;
                const f32x4 lo = *(const f32x4*)&Alf[rr * 32 + ((2 * q) ^ s8) * 4];
                const f32x4 hi = *(const f32x4*)&Alf[rr * 32 + ((2 * q + 1) ^ s8) * 4];
                union { bf16x8 v; unsigned u[4]; } cv;
                cv.u[0] = cvt_pk_bf16(lo.x, lo.y);
                cv.u[1] = cvt_pk_bf16(lo.z, lo.w);
                cv.u[2] = cvt_pk_bf16(hi.x, hi.y);
                cv.u[3] = cvt_pk_bf16(hi.z, hi.w);
                af[mt] = cv.v;
            } else if constexpr (AMODE == 0) {
                const unsigned short* Al = (const unsigned short*)tb;
                af[mt] = *(const bf16x8*)&Al[rr * 32 + (q ^ ((rr >> 1) & 3)) * 8];
            } else {
                const unsigned char* Al8 = (const unsigned char*)tb;
                const uint2 wv = *(const uint2*)(Al8 + rr * 32 +
                                                 (((q >> 1) ^ (rr & 1)) << 4) + ((q & 1) << 3));
                const f32x2 p0 = __builtin_amdgcn_cvt_pk_f32_fp8(wv.x, false);
                const f32x2 p1 = __builtin_amdgcn_cvt_pk_f32_fp8(wv.x, true);
                const f32x2 p2 = __builtin_amdgcn_cvt_pk_f32_fp8(wv.y, false);
                const f32x2 p3 = __builtin_amdgcn_cvt_pk_f32_fp8(wv.y, true);
                union { bf16x8 v; unsigned u[4]; } cv;
                cv.u[0] = cvt_pk_bf16(p0.x, p0.y);
                cv.u[1] = cvt_pk_bf16(p1.x, p1.y);
                cv.u[2] = cvt_pk_bf16(p2.x, p2.y);
                cv.u[3] = cvt_pk_bf16(p3.x, p3.y);
                af[mt] = cv.v;
            }
        }
        #pragma unroll
        for (int nt = 0; nt < TN; ++nt) {
            const int rr = wn * WN + nt * 16 + r;
            bfr[nt] = *(const bf16x8*)&Bl[rr * 32 + (q ^ ((rr >> 1) & 3)) * 8];
        }
        #pragma unroll
        for (int mt = 0; mt < TM; ++mt)
            #pragma unroll
            for (int nt = 0; nt < TN; ++nt)
                acc[mt][nt] = __builtin_amdgcn_mfma_f32_16x16x32_bf16(
                    af[mt], bfr[nt], acc[mt][nt], 0, 0, 0);
    };

    const int nkt = K >> 5;
    STAGE(0, 0);
    if (nkt > 1) STAGE(1, 32);
    for (int kt = 0; kt < nkt; ++kt) {
        const int buf = kt & 1;
        if (kt + 1 < nkt) wait_vmcnt<LPT>();   // tile kt done; kt+1 stays in flight
        else wait_vmcnt<0>();                  // last tile: drain
        __builtin_amdgcn_s_barrier();          // all waves: tile kt ready
        COMPUTE(buf);
        asm volatile("s_waitcnt lgkmcnt(0)" ::: "memory");  // my LDS reads returned
        __builtin_amdgcn_s_barrier();          // all waves done reading buf
        if (kt + 2 < nkt) STAGE(buf, (kt + 2) << 5);        // refill pipeline
    }

    #pragma unroll
    for (int mt = 0; mt < TM; ++mt) {
        #pragma unroll
        for (int nt = 0; nt < TN; ++nt) {
            const int gcol = col0 + wn * WN + nt * 16 + r;
            #pragma unroll
            for (int j = 0; j < 4; ++j) {
                const int grow = row0 + wm * WM + mt * 16 + q * 4 + j;
                if (grow < M) {
                    if (OUTMODE == 2)
                        ((unsigned char*)Cv)[(size_t)grow * Ncols + gcol] = f2fp8(acc[mt][nt][j]);
                    else if (OUTMODE == 1)
                        ((unsigned short*)Cv)[(size_t)grow * Ncols + gcol] = f2bf(acc[mt][nt][j]);
                    else
                        ((float*)Cv)[(size_t)grow * Ncols + gcol] = acc[mt][nt][j];
                }
            }
        }
    }
}

// ---- CSR-build bodies (device fns for grid fusion) ----
__device__ __forceinline__ void scatter_body(char* dsm, int bid,
                                             const int* __restrict__ rows,
                                             const int* __restrict__ cols,
                                             const float* __restrict__ vals,
                                             const int* __restrict__ bstart,
                                             int* __restrict__ bcursor,
                                             int2* __restrict__ tmp, int E) {
    int* lcnt = (int*)dsm;
    int* lbase = lcnt + NBMAX;
    const int t = threadIdx.x;
    const long c0 = (long)bid * SB_CH;
    for (int i = t; i < NBMAX; i += 256) lcnt[i] = 0;
    __syncthreads();
    int rank[16], b[16];
    #pragma unroll
    for (int i = 0; i < 16; ++i) {
        const long e = c0 + i * 256 + t;
        if (e < E) {
            b[i] = rows[e] >> 8;
            rank[i] = atomicAdd(&lcnt[b[i]], 1);
        }
    }
    __syncthreads();
    for (int i = t; i < NBMAX; i += 256)
        lbase[i] = lcnt[i] ? atomicAdd(&bcursor[i], lcnt[i]) : 0;
    __syncthreads();
    #pragma unroll
    for (int i = 0; i < 16; ++i) {
        const long e = c0 + i * 256 + t;
        if (e < E) {
            const int r = rows[e];
            const int pos = bstart[b[i]] + lbase[b[i]] + rank[i];
            tmp[pos] = make_int2(((r & 255) << 17) | cols[e], __float_as_int(vals[e]));
        }
    }
}

__device__ __forceinline__ void b2csr_body(char* dsm, int b,
                                           const int2* __restrict__ tmp,
                                           const int* __restrict__ bstart,
                                           int* __restrict__ rs,
                                           int2* __restrict__ edges,
                                           int N, int nb, int E) {
    int* rcnt = (int*)dsm;
    int* rsc = rcnt + 256;
    const int t = threadIdx.x;
    const int s = bstart[b], e = bstart[b + 1];
    rcnt[t] = 0;
    __syncthreads();
    for (int i = s + t; i < e; i += 256)
        atomicAdd(&rcnt[tmp[i].x >> 17], 1);
    __syncthreads();
    const int v = rcnt[t];
    rsc[t] = v;
    __syncthreads();
    for (int o = 1; o < 256; o <<= 1) {
        const int y = (t >= o) ? rsc[t - o] : 0;
        __syncthreads();
        rsc[t] += y;
        __syncthreads();
    }
    const int excl = rsc[t] - v;
    const int grow = b * 256 + t;
    if (grow < N) rs[grow] = s + excl;
    if (b == nb - 1 && t == 0) rs[N] = E;
    __syncthreads();
    rcnt[t] = s + excl;
    __syncthreads();
    for (int i = s + t; i < e; i += 256) {
        const int2 x = tmp[i];
        const int pos = atomicAdd(&rcnt[x.x >> 17], 1);
        edges[pos] = make_int2(x.x & 0x1FFFF, x.y);
    }
}

// ---- fused launches: gemm1 half ∥ CSR-build phase (independent pipes) ----
template <int BM, int BN, int OUTMODE, int AMODE>
__global__ __launch_bounds__(256) void gemm_plus_scatter(
        const void* __restrict__ Av, const unsigned short* __restrict__ BT,
        void* __restrict__ Cv, int M, int Ncols, int K, int ncb,
        int gemmBlocks, int gemmOffset, int gemmTotal,
        const int* __restrict__ rows, const int* __restrict__ cols,
        const float* __restrict__ vals, const int* __restrict__ bstart,
        int* __restrict__ bcursor, int2* __restrict__ tmp, int E) {
    extern __shared__ __align__(16) char dsm[];
    if ((int)blockIdx.x < gemmBlocks)
        gemm_body<BM, BN, OUTMODE, AMODE>(dsm, blockIdx.x + gemmOffset, gemmTotal,
                                          Av, BT, Cv, M, Ncols, K, ncb);
    else
        scatter_body(dsm, blockIdx.x - gemmBlocks, rows, cols, vals, bstart, bcursor, tmp, E);
}

template <int BM, int BN, int OUTMODE, int AMODE>
__global__ __launch_bounds__(256) void gemm_plus_csr(
        const void* __restrict__ Av, const unsigned short* __restrict__ BT,
        void* __restrict__ Cv, int M, int Ncols, int K, int ncb,
        int gemmBlocks, int gemmOffset, int gemmTotal,
        const int2* __restrict__ tmp, const int* __restrict__ bstart,
        int* __restrict__ rs, int2* __restrict__ edges, int N, int nb, int E) {
    extern __shared__ __align__(16) char dsm[];
    if ((int)blockIdx.x < gemmBlocks)
        gemm_body<BM, BN, OUTMODE, AMODE>(dsm, blockIdx.x + gemmOffset, gemmTotal,
                                          Av, BT, Cv, M, Ncols, K, ncb);
    else
        b2csr_body(dsm, blockIdx.x - gemmBlocks, tmp, bstart, rs, edges, N, nb, E);
}

// standalone gemm (layer 2)
template <int BM, int BN, int OUTMODE, int AMODE>
__global__ __launch_bounds__(256) void gemm_mfma(const void* __restrict__ Av,
                                                 const unsigned short* __restrict__ BT,
                                                 void* __restrict__ Cv,
                                                 int M, int Ncols, int K, int ncb) {
    constexpr int ABYTES = BM * 32 * (AMODE == 1 ? 4 : (AMODE == 0 ? 2 : 1));
    constexpr int TILE = ABYTES + BN * 32 * 2;
    __shared__ __align__(16) char smem[2 * TILE];
    gemm_body<BM, BN, OUTMODE, AMODE>(smem, blockIdx.x, gridDim.x, Av, BT, Cv, M, Ncols, K, ncb);
}

// fused: blocks [0,HIST_BLOCKS) bucket histogram; rest do both weight transposes
__global__ __launch_bounds__(256) void hist_and_transpose(
        const int* __restrict__ rows, int* __restrict__ bcnt, int E,
        const float* __restrict__ in1, unsigned short* __restrict__ out1, int K1, int N1,
        const float* __restrict__ in2, unsigned short* __restrict__ out2, int K2, int N2) {
    if (blockIdx.x < HIST_BLOCKS) {
        __shared__ int h[NBMAX];
        for (int i = threadIdx.x; i < NBMAX; i += 256) h[i] = 0;
        __syncthreads();
        for (long i = (long)blockIdx.x * 256 + threadIdx.x; i < E;
             i += (long)HIST_BLOCKS * 256)
            atomicAdd(&h[rows[i] >> 8], 1);
        __syncthreads();
        for (int i = threadIdx.x; i < NBMAX; i += 256)
            if (h[i]) atomicAdd(&bcnt[i], h[i]);
    } else {
        int idx = (blockIdx.x - HIST_BLOCKS) * 256 + threadIdx.x;
        const int t1 = K1 * N1;
        if (idx < t1) {
            const int k = idx / N1, n = idx % N1;
            out1[(size_t)n * K1 + k] = f2bf(in1[idx]);
        } else {
            idx -= t1;
            if (idx < K2 * N2) {
                const int k = idx / N2, n = idx % N2;
                out2[(size_t)n * K2 + k] = f2bf(in2[idx]);
            }
        }
    }
}

__global__ __launch_bounds__(512) void bucket_scan(const int* __restrict__ bcnt,
                                                   int* __restrict__ bstart, int nb) {
    __shared__ int s[NBMAX];
    const int t = threadIdx.x;
    const int v = (t < nb) ? bcnt[t] : 0;
    s[t] = v;
    __syncthreads();
    for (int o = 1; o < NBMAX; o <<= 1) {
        const int y = (t >= o) ? s[t - o] : 0;
        __syncthreads();
        s[t] += y;
        __syncthreads();
    }
    if (t < nb) bstart[t] = s[t] - v;
    if (t == nb - 1) bstart[nb] = s[t];
}

// ---- CSR spmm ----
// F=256 (fp8 X row-major), fused bias+relu, fp8 out.  16-edge pipeline:
// edge records as wave-uniform int4 pairs; 16 independent 4B/lane gathers
// in flight per iteration.
__global__ __launch_bounds__(256) void spmm_csr256_relu(const int2* __restrict__ edges,
                                                        const int* __restrict__ rs,
                                                        const unsigned char* __restrict__ X,
                                                        const float* __restrict__ bias,
                                                        unsigned char* __restrict__ Y, int N) {
    const int row = __builtin_amdgcn_readfirstlane(blockIdx.x * 4 + (threadIdx.x >> 6));
    if (row >= N) return;
    const int lane = threadIdx.x & 63;
    const int s = rs[row], e = rs[row + 1];
    float a0 = 0.f, a1 = 0.f, a2 = 0.f, a3 = 0.f;
    int i = s;

#define SP256_ONE(col, vbits)                                                 \
    {                                                                         \
        const unsigned xw = ((const unsigned*)(X + (size_t)(col) * 256))[lane]; \
        const float v = __int_as_float(vbits);                                \
        const f32x2 l = __builtin_amdgcn_cvt_pk_f32_fp8(xw, false);           \
        const f32x2 h = __builtin_amdgcn_cvt_pk_f32_fp8(xw, true);            \
        a0 += v * l.x; a1 += v * l.y; a2 += v * h.x; a3 += v * h.y;           \
    }

    if ((i & 1) && i < e) {   // peel to 16B-align the int4 edge loads
        const int2 e0 = edges[i];
        SP256_ONE(e0.x, e0.y);
        ++i;
    }
    for (; i + 16 <= e; i += 16) {
        int4 qv[8];
        #pragma unroll
        for (int j = 0; j < 8; ++j) qv[j] = *(const int4*)(edges + i + 2 * j);
        unsigned xw[16];
        #pragma unroll
        for (int j = 0; j < 8; ++j) {
            xw[2 * j]     = ((const unsigned*)(X + (size_t)qv[j].x * 256))[lane];
            xw[2 * j + 1] = ((const unsigned*)(X + (size_t)qv[j].z * 256))[lane];
        }
        #pragma unroll
        for (int j = 0; j < 8; ++j) {
            const float va = __int_as_float(qv[j].y);
            const float vb = __int_as_float(qv[j].w);
            const f32x2 la = __builtin_amdgcn_cvt_pk_f32_fp8(xw[2 * j], false);
            const f32x2 ha = __builtin_amdgcn_cvt_pk_f32_fp8(xw[2 * j], true);
            const f32x2 lb = __builtin_amdgcn_cvt_pk_f32_fp8(xw[2 * j + 1], false);
            const f32x2 hb = __builtin_amdgcn_cvt_pk_f32_fp8(xw[2 * j + 1], true);
            a0 += va * la.x + vb * lb.x;
            a1 += va * la.y + vb * lb.y;
            a2 += va * ha.x + vb * hb.x;
            a3 += va * ha.y + vb * hb.y;
        }
    }
    for (; i + 8 <= e; i += 8) {
        int4 qv[4];
        #pragma unroll
        for (int j = 0; j < 4; ++j) qv[j] = *(const int4*)(edges + i + 2 * j);
        unsigned xw[8];
        #pragma unroll
        for (int j = 0; j < 4; ++j) {
            xw[2 * j]     = ((const unsigned*)(X + (size_t)qv[j].x * 256))[lane];
            xw[2 * j + 1] = ((const unsigned*)(X + (size_t)qv[j].z * 256))[lane];
        }
        #pragma unroll
        for (int j = 0; j < 4; ++j) {
            const float va = __int_as_float(qv[j].y);
            const float vb = __int_as_float(qv[j].w);
            const f32x2 la = __builtin_amdgcn_cvt_pk_f32_fp8(xw[2 * j], false);
            const f32x2 ha = __builtin_amdgcn_cvt_pk_f32_fp8(xw[2 * j], true);
            const f32x2 lb = __builtin_amdgcn_cvt_pk_f32_fp8(xw[2 * j + 1], false);
            const f32x2 hb = __builtin_amdgcn_cvt_pk_f32_fp8(xw[2 * j + 1], true);
            a0 += va * la.x + vb * lb.x;
            a1 += va * la.y + vb * lb.y;
            a2 += va * ha.x + vb * hb.x;
            a3 += va * ha.y + vb * hb.y;
        }
    }
    for (; i < e; ++i) {
        const int2 e0 = edges[i];
        SP256_ONE(e0.x, e0.y);
    }
#undef SP256_ONE

    const float4 bb = ((const float4*)bias)[lane];
    unsigned wo = __builtin_amdgcn_cvt_pk_fp8_f32(fmaxf(a0 + bb.x, 0.f),
                                                  fmaxf(a1 + bb.y, 0.f), 0, false);
    wo = __builtin_amdgcn_cvt_pk_fp8_f32(fmaxf(a2 + bb.z, 0.f),
                                         fmaxf(a3 + bb.w, 0.f), wo, true);
    ((unsigned*)(Y + (size_t)row * 256))[lane] = wo;
}

// F=64 (fp8 X row-major), fused bias + log_softmax, fp32 out. 8-edge unroll.
__global__ __launch_bounds__(256) void spmm_csr64_lsm(const int2* __restrict__ edges,
                                                      const int* __restrict__ rs,
                                                      const unsigned char* __restrict__ X,
                                                      const float* __restrict__ bias,
                                                      float* __restrict__ out, int N) {
    const int row = __builtin_amdgcn_readfirstlane(blockIdx.x * 4 + (threadIdx.x >> 6));
    if (row >= N) return;
    const int lane = threadIdx.x & 63;
    const int s = rs[row], e = rs[row + 1];
    float acc = 0.f;
    int i = s;

#define SP64_ONE(col, vbits)                                                  \
    {                                                                         \
        const int u = X[(size_t)(col) * 64 + lane];                           \
        acc += __int_as_float(vbits) * __builtin_amdgcn_cvt_f32_fp8(u, 0);    \
    }

    if ((i & 1) && i < e) {
        const int2 e0 = edges[i];
        SP64_ONE(e0.x, e0.y);
        ++i;
    }
    for (; i + 8 <= e; i += 8) {
        const int4 q0 = *(const int4*)(edges + i);
        const int4 q1 = *(const int4*)(edges + i + 2);
        const int4 q2 = *(const int4*)(edges + i + 4);
        const int4 q3 = *(const int4*)(edges + i + 6);
        const int u0 = X[(size_t)q0.x * 64 + lane];
        const int u1 = X[(size_t)q0.z * 64 + lane];
        const int u2 = X[(size_t)q1.x * 64 + lane];
        const int u3 = X[(size_t)q1.z * 64 + lane];
        const int u4 = X[(size_t)q2.x * 64 + lane];
        const int u5 = X[(size_t)q2.z * 64 + lane];
        const int u6 = X[(size_t)q3.x * 64 + lane];
        const int u7 = X[(size_t)q3.z * 64 + lane];
        acc += __int_as_float(q0.y) * __builtin_amdgcn_cvt_f32_fp8(u0, 0)
             + __int_as_float(q0.w) * __builtin_amdgcn_cvt_f32_fp8(u1, 0)
             + __int_as_float(q1.y) * __builtin_amdgcn_cvt_f32_fp8(u2, 0)
             + __int_as_float(q1.w) * __builtin_amdgcn_cvt_f32_fp8(u3, 0)
             + __int_as_float(q2.y) * __builtin_amdgcn_cvt_f32_fp8(u4, 0)
             + __int_as_float(q2.w) * __builtin_amdgcn_cvt_f32_fp8(u5, 0)
             + __int_as_float(q3.y) * __builtin_amdgcn_cvt_f32_fp8(u6, 0)
             + __int_as_float(q3.w) * __builtin_amdgcn_cvt_f32_fp8(u7, 0);
    }
    for (; i < e; ++i) {
        const int2 e0 = edges[i];
        SP64_ONE(e0.x, e0.y);
    }
#undef SP64_ONE

    float v = acc + bias[lane];
    float m = v;
    #pragma unroll
    for (int o = 32; o; o >>= 1) m = fmaxf(m, __shfl_xor(m, o));
    const float ex = __expf(v - m);
    float ssum = ex;
    #pragma unroll
    for (int o = 32; o; o >>= 1) ssum += __shfl_xor(ssum, o);
    out[(size_t)row * 64 + lane] = v - m - __logf(ssum);
}

extern "C" void kernel_launch(void* const* d_in, const int* in_sizes, int n_in,
                              void* d_out, int out_size, void* d_ws, size_t ws_size,
                              hipStream_t stream) {
    const float* x    = (const float*)d_in[0];
    const int*   erow = (const int*)d_in[1];
    const int*   ecol = (const int*)d_in[2];
    const float* eval = (const float*)d_in[3];
    const float* W1   = (const float*)d_in[4];
    const float* b1   = (const float*)d_in[5];
    const float* W2   = (const float*)d_in[6];
    const float* b2   = (const float*)d_in[7];
    float* out = (float*)d_out;

    const int E      = in_sizes[1];
    const int nhid   = in_sizes[5];              // 256
    const int nclass = in_sizes[7];              // 64
    const int nfeat  = in_sizes[4] / nhid;       // 512
    const int N      = in_sizes[0] / nfeat;      // 100000

    // workspace layout (~78 MB, aliased regions noted)
    char* w = (char*)d_ws;
    unsigned char* h1q = (unsigned char*)w;       // [N][256] fp8 (25.6 MB)
    int2* tmp = (int2*)w;                         // aliases h1q during CSR build (E*8)
    w += (size_t)N * nhid;
    unsigned char* h0q = (unsigned char*)w;       // [N][256] fp8 (25.6 MB)
    unsigned char* h2q = h0q;                     // aliases h0q after spmm1 ([N][64] fp8)
    w += (size_t)N * nhid;
    int2* edges = (int2*)w;                       w += (size_t)E * 8;
    int* rs = (int*)w;                            w += (size_t)(N + 1) * 4;
    int* bcnt = (int*)w;                          w += NBMAX * 4;
    int* bcursor = (int*)w;                       w += NBMAX * 4;
    int* bstart = (int*)w;                        w += (NBMAX + 1) * 4;
    unsigned short* W1T = (unsigned short*)w;     w += (size_t)nfeat * nhid * 2;
    unsigned short* W2T = (unsigned short*)w;     w += (size_t)nhid * nclass * 2;

    const int nb = (N + 255) >> 8;                // 391 buckets of 256 rows
    const int nsb = (E + SB_CH - 1) / SB_CH;      // 782 scatter blocks

    // phase 0: hist + weight transposes (fused), then bucket scan
    hipMemsetAsync(bcnt, 0, (size_t)2 * NBMAX * sizeof(int), stream);  // bcnt + bcursor
    const int tc_total = nfeat * nhid + nhid * nclass;
    const int ht_grid = HIST_BLOCKS + (tc_total + 255) / 256;
    hist_and_transpose<<<ht_grid, 256, 0, stream>>>(erow, bcnt, E,
                                                    W1, W1T, nfeat, nhid,
                                                    W2, W2T, nhid, nclass);
    bucket_scan<<<1, NBMAX, 0, stream>>>(bcnt, bstart, nb);

    // layer-1 gemm split in half, each half grid-fused with an independent
    // CSR-build phase (MFMA/LDS pipe ∥ fabric/atomic pipe):
    //   launch A: gemm1[0,half) ∥ scatter_bucket
    //   launch B: gemm1[half,ng1) ∥ bucket_to_csr (tmp complete via stream order)
    constexpr int DYN_LDS = 2 * (128 * 32 * 4 + 128 * 32 * 2);   // 49152 B
    const int ncb1 = nhid / 128;
    const int ng1 = ((N + 127) / 128) * ncb1;
    const int half1 = ng1 / 2;
    gemm_plus_scatter<128, 128, 2, 1><<<half1 + nsb, 256, DYN_LDS, stream>>>(
        x, W1T, h0q, N, nhid, nfeat, ncb1, half1, 0, ng1,
        erow, ecol, eval, bstart, bcursor, tmp, E);
    gemm_plus_csr<128, 128, 2, 1><<<(ng1 - half1) + nb, 256, DYN_LDS, stream>>>(
        x, W1T, h0q, N, nhid, nfeat, ncb1, ng1 - half1, half1, ng1,
        tmp, bstart, rs, edges, N, nb, E);

    // h1q = fp8(relu(spmm(h0q) + b1))   (h1q aliases tmp: last tmp read was launch B)
    spmm_csr256_relu<<<(N + 3) / 4, 256, 0, stream>>>(edges, rs, h0q, b1, h1q, N);

    // layer 2: h2q = fp8(h1q @ W2), fp8 A dequantized at fragment read
    const int ng2 = (N + 127) / 128;
    gemm_mfma<128, 64, 2, 2><<<ng2, 256, 0, stream>>>(h1q, W2T, h2q, N, nclass, nhid, 1);
    // out = log_softmax(spmm(h2q) + b2)
    spmm_csr64_lsm<<<(N + 3) / 4, 256, 0, stream>>>(edges, rs, h2q, b2, out, N);
}